// Round 4
// baseline (21523.116 us; speedup 1.0000x reference)
//
#include <hip/hip_runtime.h>
#include <math.h>

#define NB 512      // batch
#define NT 512      // time
#define NCTRL 256
#define NWORD 128
#define NMEM 128
#define NDIN 64
#define NACT 448    // x(64) | read(128) | ctrl(256)
#define EPSF 1e-6f

// fp16 weight panel, CHUNK-TRANSPOSED layout (identical to prior rounds):
//   element(region, kc, col, e) at region_base + (kc*NCOLS + col)*8 + e
#define H_WA   0        // rz:    56 kc x 512 cols x 8
#define H_WNI  229376   // inn:   24 kc x 256 cols x 8
#define H_WNH  278528   // hn:    32 kc x 256 cols x 8
#define H_WH   344064   // heads: 32 kc x 512 cols x 8 (key|erase|add|beta|pad)
#define H_TOTAL 475136
#define B_BA   0        // [512] b_ih+b_hh (r,z)
#define B_BNI  512      // [256]
#define B_BNH  768      // [256]
#define B_BH   1024     // [512]
#define B_TOTAL 1536
#define WS_BYTES (H_TOTAL * 2 + B_TOTAL * 4)

// prefetch depths (VGPR cost: (PFA+PFX)*4 = 96 regs live across memory phase)
#define PFA 16
#define PFX 8
#define PFH 8

typedef _Float16 h2 __attribute__((ext_vector_type(2)));
typedef _Float16 h8 __attribute__((ext_vector_type(8)));
union H8 { h8 v; h2 d[4]; };

__device__ __forceinline__ float sigf(float x) { return 1.0f / (1.0f + expf(-x)); }
__device__ __forceinline__ float softplusf(float x) {
    return (x > 15.0f) ? x : log1pf(expf(x));
}
__device__ __forceinline__ float fdot2(h2 a, h2 b, float c) {
#if __has_builtin(__builtin_amdgcn_fdot2)
    return __builtin_amdgcn_fdot2(a, b, c, false);
#else
    return fmaf((float)a[0], (float)b[0], fmaf((float)a[1], (float)b[1], c));
#endif
}

// lgkm-only barrier: orders LDS traffic without draining vmcnt, so global
// weight prefetches stay in flight across phase boundaries. All in-loop
// inter-thread communication is via LDS; per-value vmcnt waits are inserted
// by the compiler for each thread's own global loads.
__device__ __forceinline__ void barL() {
    asm volatile("s_waitcnt lgkmcnt(0)\n\ts_barrier" ::: "memory");
}

__global__ __launch_bounds__(256) void prep_kernel(
    const float* __restrict__ Wih, const float* __restrict__ bih,
    const float* __restrict__ Whh, const float* __restrict__ bhh,
    const float* __restrict__ Wkey, const float* __restrict__ bkey,
    const float* __restrict__ Wbeta, const float* __restrict__ bbeta,
    const float* __restrict__ Wer, const float* __restrict__ ber,
    const float* __restrict__ Wadd, const float* __restrict__ badd,
    _Float16* __restrict__ wsH, float* __restrict__ wsB)
{
    int i = blockIdx.x * 256 + threadIdx.x;
    if (i < H_TOTAL) {
        float v;
        if (i < H_WNI) {                       // rz [kc][512][8]
            int ch = i >> 3, e = i & 7;
            int kc = ch >> 9, col = ch & 511;
            int k = kc * 8 + e;
            v = (k < 192) ? Wih[col * 192 + k] : Whh[col * 256 + (k - 192)];
        } else if (i < H_WNH) {                // inn [kc][256][8], k<192
            int i2 = i - H_WNI; int ch = i2 >> 3, e = i2 & 7;
            int kc = ch >> 8, col = ch & 255;
            v = Wih[(512 + col) * 192 + kc * 8 + e];
        } else if (i < H_WH) {                 // hn [kc][256][8], k<256
            int i2 = i - H_WNH; int ch = i2 >> 3, e = i2 & 7;
            int kc = ch >> 8, col = ch & 255;
            v = Whh[(512 + col) * 256 + kc * 8 + e];
        } else {                               // heads [kc][512][8], k<256
            int i2 = i - H_WH; int ch = i2 >> 3, e = i2 & 7;
            int kc = ch >> 9, col = ch & 511;
            int k = kc * 8 + e;
            if (col < 128)       v = Wkey[col * 256 + k];
            else if (col < 256)  v = Wer[(col - 128) * 256 + k];
            else if (col < 384)  v = Wadd[(col - 256) * 256 + k];
            else if (col == 384) v = Wbeta[k];
            else                 v = 0.0f;
        }
        wsH[i] = (_Float16)v;
    } else if (i < H_TOTAL + B_TOTAL) {
        int j = i - H_TOTAL;
        float v;
        if (j < 512)        v = bih[j] + bhh[j];
        else if (j < 768)   v = bih[512 + (j - 512)];
        else if (j < 1024)  v = bhh[512 + (j - 768)];
        else {
            int c = j - 1024;
            if (c < 128)       v = bkey[c];
            else if (c < 256)  v = ber[c - 128];
            else if (c < 384)  v = badd[c - 256];
            else if (c == 384) v = bbeta[0];
            else               v = 0.0f;
        }
        wsB[j] = v;
    }
}

// Slow-path memory module (verified): __syncthreads-based.
__device__ __forceinline__ void memory_step(
    int u, bool wr, float (*M)[NWORD + 1],
    const float* keyv, const float* ev, const float* av,
    float* cosb, float* wb, float* part, float* readv, float* scal)
{
    if (u < 64) {                       // ||k||
        float s = keyv[u] * keyv[u] + keyv[u + 64] * keyv[u + 64];
        #pragma unroll
        for (int o = 32; o >= 1; o >>= 1) s += __shfl_xor(s, o);
        if (u == 0) scal[0] = 1.0f / (sqrtf(s) + EPSF);
    }
    __syncthreads();
    {                                      // cosine sim: 2 threads / row
        int rr = u >> 1, hh = u & 1;
        const float* Mr = &M[rr][hh * 64];
        const float4* kk4 = (const float4*)(keyv + hh * 64);
        float s2 = 0.f, sc = 0.f;
        #pragma unroll
        for (int p = 0; p < 16; ++p) {
            float4 k4 = kk4[p];
            float m0 = Mr[4 * p], m1 = Mr[4 * p + 1], m2 = Mr[4 * p + 2], m3 = Mr[4 * p + 3];
            s2 = fmaf(m0, m0, s2); sc = fmaf(m0, k4.x, sc);
            s2 = fmaf(m1, m1, s2); sc = fmaf(m1, k4.y, sc);
            s2 = fmaf(m2, m2, s2); sc = fmaf(m2, k4.z, sc);
            s2 = fmaf(m3, m3, s2); sc = fmaf(m3, k4.w, sc);
        }
        s2 += __shfl_xor(s2, 1);
        sc += __shfl_xor(sc, 1);
        if (hh == 0) cosb[rr] = sc * scal[0] / (sqrtf(s2) + EPSF);
    }
    __syncthreads();
    if (u < 64) {                       // softmax over 128 logits
        float beta = scal[1];
        float l0 = beta * cosb[u], l1 = beta * cosb[u + 64];
        float mx = fmaxf(l0, l1);
        #pragma unroll
        for (int o = 32; o >= 1; o >>= 1) mx = fmaxf(mx, __shfl_xor(mx, o));
        float e0 = expf(l0 - mx), e1 = expf(l1 - mx);
        float s = e0 + e1;
        #pragma unroll
        for (int o = 32; o >= 1; o >>= 1) s += __shfl_xor(s, o);
        float inv = 1.0f / s;
        wb[u] = e0 * inv;
        wb[u + 64] = e1 * inv;
    }
    __syncthreads();
    {   // FUSED read+update
        int j = u & 127, rh = u >> 7;
        float ej = ev[j], aj = av[j];
        const float4* wb4 = (const float4*)(wb + rh * 64);
        float p = 0.f;
        #pragma unroll
        for (int pq = 0; pq < 16; ++pq) {
            float4 w4 = wb4[pq];
            int r = rh * 64 + 4 * pq;
            float m0 = M[r][j], m1 = M[r + 1][j], m2 = M[r + 2][j], m3 = M[r + 3][j];
            p = fmaf(w4.x, m0, p);
            p = fmaf(w4.y, m1, p);
            p = fmaf(w4.z, m2, p);
            p = fmaf(w4.w, m3, p);
            if (wr) {
                M[r][j]     = fmaf(-w4.x, fmaf(ej, m0, -aj), m0);
                M[r + 1][j] = fmaf(-w4.y, fmaf(ej, m1, -aj), m1);
                M[r + 2][j] = fmaf(-w4.z, fmaf(ej, m2, -aj), m2);
                M[r + 3][j] = fmaf(-w4.w, fmaf(ej, m3, -aj), m3);
            }
        }
        part[rh * 128 + j] = p;
    }
    __syncthreads();
    if (wr && u < 128) readv[u] = part[u] + part[128 + u];
}

#define DOT_RZ(WSRC) do { H8 w_; w_.v = (WSRC); \
    a0 = fdot2(x0.d[0], w_.d[0], a0); c0 = fdot2(x0.d[1], w_.d[1], c0); \
    a0 = fdot2(x0.d[2], w_.d[2], a0); c0 = fdot2(x0.d[3], w_.d[3], c0); \
    a1 = fdot2(x1.d[0], w_.d[0], a1); c1 = fdot2(x1.d[1], w_.d[1], c1); \
    a1 = fdot2(x1.d[2], w_.d[2], a1); c1 = fdot2(x1.d[3], w_.d[3], c1); } while (0)

#define DOT_AUX(WSRC) do { H8 w_; w_.v = (WSRC); \
    e0 = fdot2(x0.d[0], w_.d[0], e0); f0 = fdot2(x0.d[1], w_.d[1], f0); \
    e0 = fdot2(x0.d[2], w_.d[2], e0); f0 = fdot2(x0.d[3], w_.d[3], f0); \
    e1 = fdot2(x1.d[0], w_.d[0], e1); f1 = fdot2(x1.d[1], w_.d[1], f1); \
    e1 = fdot2(x1.d[2], w_.d[2], e1); f1 = fdot2(x1.d[3], w_.d[3], f1); } while (0)

#define DOT_HD(WSRC) do { H8 w_; w_.v = (WSRC); \
    h0 = fdot2(x0.d[0], w_.d[0], h0); d0 = fdot2(x0.d[1], w_.d[1], d0); \
    h0 = fdot2(x0.d[2], w_.d[2], h0); d0 = fdot2(x0.d[3], w_.d[3], d0); \
    h1 = fdot2(x1.d[0], w_.d[0], h1); d1 = fdot2(x1.d[1], w_.d[1], d1); \
    h1 = fdot2(x1.d[2], w_.d[2], h1); d1 = fdot2(x1.d[3], w_.d[3], d1); } while (0)

#define LOADX(KC) H8 x0; x0.v = A0[KC]; H8 x1; x1.v = A1[KC]

// issue next sweep's weight prefetch + x(t) load; pinned before the next
// barL by its memory clobber, completes during the memory phase.
#define ISSUE_SWEEP_PF(TS) do { \
    int tn_ = ((TS) < NT) ? (TS) : 0; \
    if (u >= 128 && u < 192) xf = data[((long)tn_ * NB + b) * NDIN + (u - 128)]; \
    _Pragma("unroll") \
    for (int i_ = 0; i_ < PFA; ++i_) pfA[i_] = pA[i_ * 512 + t]; \
    if (t < 256) { \
        _Pragma("unroll") \
        for (int i_ = 0; i_ < PFX; ++i_) pfX[i_] = pI[i_ * 256 + u]; \
    } else { \
        _Pragma("unroll") \
        for (int i_ = 0; i_ < PFX; ++i_) pfX[i_] = pH[i_ * 256 + u]; \
    } \
} while (0)

// 2 rows / 512-thread block (shared weight loads), now with lgkm-only
// barriers + cross-phase weight prefetch so L2 delivery overlaps the
// LDS-bound memory phase. 1 WG/CU (LDS ~149 KB), 2 waves/SIMD -> VGPR
// budget up to 256 is free; prefetch uses ~96 of it.
__global__ __launch_bounds__(512, 2) void ntm_fast3(
    const float* __restrict__ data, const int* __restrict__ batch_sizes,
    const int* __restrict__ unsort, const float* __restrict__ M0,
    const _Float16* __restrict__ wsH, const float* __restrict__ wsB,
    float* __restrict__ out)
{
    __shared__ float M[2][NMEM][NWORD + 1];               // 132096 B
    __shared__ __align__(16) _Float16 actH[2][NACT];      // 1792 B
    __shared__ float ctrlB[2][NCTRL];
    __shared__ float gA[2][512];
    __shared__ float iA[2][NCTRL];
    __shared__ float hA[2][NCTRL];
    __shared__ __align__(16) float readv[2][NWORD], keyv[2][NWORD], ev[2][NWORD], av[2][NWORD];
    __shared__ __align__(16) float cosb[2][NMEM], wb[2][NMEM], part[2][2 * NWORD];
    __shared__ float kn2[2][2], betav[2];
    __shared__ int len_sh[2], gpos[2];

    const int t = threadIdx.x;
    const int q = t >> 8;          // row half (0/1)
    const int u = t & 255;         // local tid within half
    const int g = blockIdx.x;
    const int b = 2 * g + q;       // this half's packed row

    if (t < 2) {
        int bb = 2 * g + t;
        int L = 0;
        for (int s = 0; s < NT; ++s) L += (batch_sizes[s] > bb);
        len_sh[t] = L;
    }
    {   // inverse permutation: find out-position of each packed row
        int ug = unsort[t];                 // t in [0,512) == NB
        if (ug == 2 * g)     gpos[0] = t;
        if (ug == 2 * g + 1) gpos[1] = t;
    }
    for (int i = t; i < 2 * NMEM * NWORD; i += 512) {
        int ii = i & (NMEM * NWORD - 1);
        M[i >> 14][ii >> 7][ii & 127] = M0[ii];
    }
    ctrlB[q][u] = 0.0f;
    actH[q][192 + u] = (_Float16)0.0f;
    if (u < NWORD) readv[q][u] = 0.0f;
    __syncthreads();
    const int len0 = len_sh[0], len1 = len_sh[1];   // len0 >= len1 (packed order)

    const float bRZ  = wsB[B_BA + t];
    const float bAux = (t < 256) ? wsB[B_BNI + u] : wsB[B_BNH + u];
    const float bHD  = wsB[B_BH + t];

    const h8* __restrict__ pA  = (const h8*)(wsH + H_WA);
    const h8* __restrict__ pI  = (const h8*)(wsH + H_WNI);
    const h8* __restrict__ pH  = (const h8*)(wsH + H_WNH);
    const h8* __restrict__ pHD = (const h8*)(wsH + H_WH);
    const h8* A0 = (const h8*)actH[0];
    const h8* A1 = (const h8*)actH[1];

    h8 pfA[PFA];
    h8 pfX[PFX];
    float xf = 0.0f;
    ISSUE_SWEEP_PF(0);          // prologue prefetch (x(0) + first chunks)

    for (int ts = 0; ts < len0; ++ts) {
        const bool wr = (q == 0) | (ts < len1);
        // ---- stage activations as fp16 (state masters stay fp32)
        if (u < 128)      actH[q][64 + u] = (_Float16)readv[q][u];
        else if (u < 192) actH[q][u - 128] = (_Float16)xf;
        barL();

        // ---- fused sweep: rz col t (both rows) + aux col u
        float a0 = bRZ, c0 = 0.f, a1 = bRZ, c1 = 0.f;
        float e0 = bAux, f0 = 0.f, e1 = bAux, f1 = 0.f;
        if (t < 256) {
            #pragma unroll
            for (int kc = 0; kc < PFX; ++kc) {          // prefetched w + wn
                LOADX(kc);
                DOT_RZ(pfA[kc]); DOT_AUX(pfX[kc]);
            }
            #pragma unroll
            for (int kc = PFX; kc < PFA; ++kc) {        // prefetched w
                LOADX(kc);
                DOT_RZ(pfA[kc]); DOT_AUX(pI[kc * 256 + u]);
            }
            #pragma unroll
            for (int kc = PFA; kc < 24; ++kc) {
                LOADX(kc);
                DOT_RZ(pA[kc * 512 + t]); DOT_AUX(pI[kc * 256 + u]);
            }
            #pragma unroll 4
            for (int kc = 24; kc < 56; ++kc) {          // rz only
                LOADX(kc);
                DOT_RZ(pA[kc * 512 + t]);
            }
        } else {
            #pragma unroll
            for (int kc = 0; kc < PFA; ++kc) {          // prefetched w
                LOADX(kc);
                DOT_RZ(pfA[kc]);
            }
            #pragma unroll
            for (int kc = PFA; kc < 24; ++kc) {
                LOADX(kc);
                DOT_RZ(pA[kc * 512 + t]);
            }
            #pragma unroll
            for (int kc = 24; kc < 24 + PFX; ++kc) {    // prefetched wn
                LOADX(kc);
                DOT_RZ(pA[kc * 512 + t]); DOT_AUX(pfX[kc - 24]);
            }
            #pragma unroll 4
            for (int kc = 24 + PFX; kc < 56; ++kc) {
                LOADX(kc);
                DOT_RZ(pA[kc * 512 + t]); DOT_AUX(pH[(kc - 24) * 256 + u]);
            }
        }
        // heads prefetch: issue before LDS writes, overlaps gates phase
        h8 pfHd[PFH];
        #pragma unroll
        for (int i = 0; i < PFH; ++i) pfHd[i] = pHD[i * 512 + t];

        gA[0][t] = a0 + c0;
        gA[1][t] = a1 + c1;
        if (t < 256) { iA[0][u] = e0 + f0; iA[1][u] = e1 + f1; }
        else         { hA[0][u] = e0 + f0; hA[1][u] = e1 + f1; }
        barL();

        {   // gate combine: thread (q,u) owns ctrl element u of row q
            float rg = sigf(gA[q][u]);
            float zg = sigf(gA[q][NCTRL + u]);
            float ng = tanhf(fmaf(rg, hA[q][u], iA[q][u]));
            float cold = ctrlB[q][u];
            float cnew = fmaf(zg, cold - ng, ng);
            if (wr) {
                ctrlB[q][u] = cnew;
                actH[q][192 + u] = (_Float16)cnew;
            }
        }
        barL();

        // ---- heads: col t for both rows, 32 chunks over new ctrl
        float h0 = bHD, d0 = 0.f, h1 = bHD, d1 = 0.f;
        #pragma unroll
        for (int kc = 0; kc < PFH; ++kc) {
            LOADX(24 + kc);
            DOT_HD(pfHd[kc]);
        }
        #pragma unroll 4
        for (int kc = PFH; kc < 32; ++kc) {
            LOADX(24 + kc);
            DOT_HD(pHD[kc * 512 + t]);
        }
        h0 += d0; h1 += d1;
        if (t < 128) {
            float k0 = tanhf(h0), k1 = tanhf(h1);
            keyv[0][t] = k0; keyv[1][t] = k1;
            // fold ||k||^2 into this phase: per-wave butterfly, 2 partials/row
            float s0 = k0 * k0, s1 = k1 * k1;
            #pragma unroll
            for (int o = 32; o >= 1; o >>= 1) {
                s0 += __shfl_xor(s0, o);
                s1 += __shfl_xor(s1, o);
            }
            if ((t & 63) == 0) { kn2[0][t >> 6] = s0; kn2[1][t >> 6] = s1; }
        }
        else if (t < 256)  { ev[0][t - 128] = sigf(h0); ev[1][t - 128] = sigf(h1); }
        else if (t < 384)  { av[0][t - 256] = h0;       av[1][t - 256] = h1; }
        else if (t == 384) { betav[0] = softplusf(h0);  betav[1] = softplusf(h1); }
        barL();

        // ---- memory: cosine sim (2 threads / mem-row)
        {
            float invk = 1.0f / (sqrtf(kn2[q][0] + kn2[q][1]) + EPSF);
            int rr = u >> 1, hh = u & 1;
            const float* Mr = &M[q][rr][hh * 64];
            const float4* kk4 = (const float4*)(&keyv[q][hh * 64]);
            float s2 = 0.f, sc = 0.f;
            #pragma unroll
            for (int p = 0; p < 16; ++p) {
                float4 k4 = kk4[p];
                float m0 = Mr[4 * p], m1 = Mr[4 * p + 1], m2 = Mr[4 * p + 2], m3 = Mr[4 * p + 3];
                s2 = fmaf(m0, m0, s2); sc = fmaf(m0, k4.x, sc);
                s2 = fmaf(m1, m1, s2); sc = fmaf(m1, k4.y, sc);
                s2 = fmaf(m2, m2, s2); sc = fmaf(m2, k4.z, sc);
                s2 = fmaf(m3, m3, s2); sc = fmaf(m3, k4.w, sc);
            }
            s2 += __shfl_xor(s2, 1);
            sc += __shfl_xor(sc, 1);
            if (hh == 0) cosb[q][rr] = sc * invk / (sqrtf(s2) + EPSF);
        }
        barL();

        // ---- softmax over 128 logits (64 threads per half)
        if (u < 64) {
            float beta = betav[q];
            float l0 = beta * cosb[q][u], l1 = beta * cosb[q][u + 64];
            float mx = fmaxf(l0, l1);
            #pragma unroll
            for (int o = 32; o >= 1; o >>= 1) mx = fmaxf(mx, __shfl_xor(mx, o));
            float se0 = expf(l0 - mx), se1 = expf(l1 - mx);
            float s = se0 + se1;
            #pragma unroll
            for (int o = 32; o >= 1; o >>= 1) s += __shfl_xor(s, o);
            float inv = 1.0f / s;
            wb[q][u] = se0 * inv;
            wb[q][u + 64] = se1 * inv;
        }
        // issue next-step sweep prefetch; delivery overlaps softmax + fused M
        ISSUE_SWEEP_PF(ts + 1);
        barL();

        // ---- FUSED read+update
        {
            int j = u & 127, rh = u >> 7;
            float ej = ev[q][j], aj = av[q][j];
            const float4* wb4 = (const float4*)(&wb[q][rh * 64]);
            float p = 0.f;
            #pragma unroll
            for (int pq = 0; pq < 16; ++pq) {
                float4 w4 = wb4[pq];
                int r = rh * 64 + 4 * pq;
                float m0 = M[q][r][j], m1 = M[q][r + 1][j], m2 = M[q][r + 2][j], m3 = M[q][r + 3][j];
                p = fmaf(w4.x, m0, p);
                p = fmaf(w4.y, m1, p);
                p = fmaf(w4.z, m2, p);
                p = fmaf(w4.w, m3, p);
                if (wr) {
                    M[q][r][j]     = fmaf(-w4.x, fmaf(ej, m0, -aj), m0);
                    M[q][r + 1][j] = fmaf(-w4.y, fmaf(ej, m1, -aj), m1);
                    M[q][r + 2][j] = fmaf(-w4.z, fmaf(ej, m2, -aj), m2);
                    M[q][r + 3][j] = fmaf(-w4.w, fmaf(ej, m3, -aj), m3);
                }
            }
            part[q][rh * 128 + j] = p;
        }
        barL();
        if (wr && u < 128) readv[q][u] = part[q][u] + part[q][128 + u];
        // readv[u] produced and consumed by thread u -> no barrier here
    }

    out[gpos[q] * NCTRL + u] = ctrlB[q][u];
    if (u < NWORD) out[NB * NCTRL + gpos[q] * NWORD + u] = readv[q][u];
}

// FALLBACK (ws too small): verified slow path.
__global__ __launch_bounds__(256) void ntm_slow(
    const float* __restrict__ data, const int* __restrict__ batch_sizes,
    const int* __restrict__ unsort,
    const float* __restrict__ Wih, const float* __restrict__ bih,
    const float* __restrict__ Whh, const float* __restrict__ bhh,
    const float* __restrict__ Wkey, const float* __restrict__ bkey,
    const float* __restrict__ Wbeta, const float* __restrict__ bbeta,
    const float* __restrict__ Wer, const float* __restrict__ ber,
    const float* __restrict__ Wadd, const float* __restrict__ badd,
    const float* __restrict__ M0, float* __restrict__ out)
{
    __shared__ float M[NMEM][NWORD + 1];
    __shared__ float act[NACT];
    __shared__ float ctrlB[NCTRL];
    __shared__ float gpre[512], ginn[256], ghn[256], hpre[448];
    __shared__ __align__(16) float readv[NWORD], keyv[NWORD], ev[NWORD], av[NWORD];
    __shared__ __align__(16) float cosb[NMEM], wb[NMEM], part[2 * NWORD], scal[2];
    __shared__ int len_sh;

    const int tid = threadIdx.x;
    const int g = blockIdx.x;
    const int b = unsort[g];

    if (tid == 0) {
        int L = 0;
        for (int t = 0; t < NT; ++t) L += (batch_sizes[t] > b);
        len_sh = L;
    }
    for (int i = tid; i < NMEM * NWORD; i += 256)
        M[i >> 7][i & 127] = M0[i];
    ctrlB[tid] = 0.0f;
    if (tid < NWORD) readv[tid] = 0.0f;
    __syncthreads();
    const int len = len_sh;
    const int wave = tid >> 6, lane = tid & 63;

    for (int t = 0; t < len; ++t) {
        if (tid < 64)  act[tid] = data[((long)t * NB + b) * NDIN + tid];
        if (tid < 128) act[64 + tid] = readv[tid];
        act[192 + tid] = ctrlB[tid];
        __syncthreads();

        for (int j = wave; j < 512; j += 4) {
            float p = 0.f;
            for (int k = lane; k < 192; k += 64) p = fmaf(act[k], Wih[j * 192 + k], p);
            for (int k = lane; k < 256; k += 64) p = fmaf(act[192 + k], Whh[j * 256 + k], p);
            #pragma unroll
            for (int o = 32; o >= 1; o >>= 1) p += __shfl_xor(p, o);
            if (lane == 0) gpre[j] = p;
        }
        for (int j = wave; j < 256; j += 4) {
            float pi = 0.f, ph = 0.f;
            for (int k = lane; k < 192; k += 64) pi = fmaf(act[k], Wih[(512 + j) * 192 + k], pi);
            for (int k = lane; k < 256; k += 64) ph = fmaf(act[192 + k], Whh[(512 + j) * 256 + k], ph);
            #pragma unroll
            for (int o = 32; o >= 1; o >>= 1) { pi += __shfl_xor(pi, o); ph += __shfl_xor(ph, o); }
            if (lane == 0) { ginn[j] = pi; ghn[j] = ph; }
        }
        __syncthreads();
        {
            float r = sigf(gpre[tid] + bih[tid] + bhh[tid]);
            float z = sigf(gpre[256 + tid] + bih[256 + tid] + bhh[256 + tid]);
            float inn = ginn[tid] + bih[512 + tid];
            float hn  = ghn[tid] + bhh[512 + tid];
            float n = tanhf(fmaf(r, hn, inn));
            float cold = act[192 + tid];
            ctrlB[tid] = fmaf(z, cold - n, n);
        }
        __syncthreads();
        for (int j = wave; j < 385; j += 4) {
            const float* Wp; long base;
            if (j < 128)      { Wp = Wkey;  base = (long)j * 256; }
            else if (j < 256) { Wp = Wer;   base = (long)(j - 128) * 256; }
            else if (j < 384) { Wp = Wadd;  base = (long)(j - 256) * 256; }
            else              { Wp = Wbeta; base = 0; }
            float p = 0.f;
            for (int k = lane; k < 256; k += 64) p = fmaf(ctrlB[k], Wp[base + k], p);
            #pragma unroll
            for (int o = 32; o >= 1; o >>= 1) p += __shfl_xor(p, o);
            if (lane == 0) hpre[j] = p;
        }
        __syncthreads();
        if (tid < 128) {
            keyv[tid] = tanhf(hpre[tid] + bkey[tid]);
            ev[tid]   = sigf(hpre[128 + tid] + ber[tid]);
            av[tid]   = hpre[256 + tid] + badd[tid];
        }
        if (tid == 0) scal[1] = softplusf(hpre[384] + bbeta[0]);
        __syncthreads();

        memory_step(tid, true, M, keyv, ev, av, cosb, wb, part, readv, scal);
        __syncthreads();
    }

    out[g * NCTRL + tid] = ctrlB[tid];
    if (tid < NWORD) out[NB * NCTRL + g * NWORD + tid] = readv[tid];
}

extern "C" void kernel_launch(void* const* d_in, const int* in_sizes, int n_in,
                              void* d_out, int out_size, void* d_ws, size_t ws_size,
                              hipStream_t stream)
{
    const float* data       = (const float*)d_in[0];
    const int*  batch_sizes = (const int*)d_in[1];
    const int*  unsort      = (const int*)d_in[2];
    float* out = (float*)d_out;

    if (ws_size >= (size_t)WS_BYTES) {
        _Float16* wsH = (_Float16*)d_ws;
        float* wsB = (float*)((char*)d_ws + (size_t)H_TOTAL * 2);
        prep_kernel<<<(H_TOTAL + B_TOTAL + 255) / 256, 256, 0, stream>>>(
            (const float*)d_in[3], (const float*)d_in[4], (const float*)d_in[5],
            (const float*)d_in[6], (const float*)d_in[7], (const float*)d_in[8],
            (const float*)d_in[9], (const float*)d_in[10], (const float*)d_in[11],
            (const float*)d_in[12], (const float*)d_in[13], (const float*)d_in[14],
            wsH, wsB);
        ntm_fast3<<<NB / 2, 512, 0, stream>>>(data, batch_sizes, unsort,
                                              (const float*)d_in[15], wsH, wsB, out);
    } else {
        ntm_slow<<<NB, 256, 0, stream>>>(
            data, batch_sizes, unsort,
            (const float*)d_in[3], (const float*)d_in[4], (const float*)d_in[5],
            (const float*)d_in[6], (const float*)d_in[7], (const float*)d_in[8],
            (const float*)d_in[9], (const float*)d_in[10], (const float*)d_in[11],
            (const float*)d_in[12], (const float*)d_in[13], (const float*)d_in[14],
            (const float*)d_in[15], out);
    }
}

// Round 6
// 20128.587 us; speedup vs baseline: 1.0693x; 1.0693x over previous
//
#include <hip/hip_runtime.h>
#include <math.h>

#define NB 512      // batch
#define NT 512      // time
#define NCTRL 256
#define NWORD 128
#define NMEM 128
#define NDIN 64
#define NACT 448    // x(64) | read(128) | ctrl(256)
#define EPSF 1e-6f

// fp16 weight panel, CHUNK-TRANSPOSED layout (identical to prior rounds):
//   element(region, kc, col, e) at region_base + (kc*NCOLS + col)*8 + e
#define H_WA   0        // rz:    56 kc x 512 cols x 8
#define H_WNI  229376   // inn:   24 kc x 256 cols x 8
#define H_WNH  278528   // hn:    32 kc x 256 cols x 8
#define H_WH   344064   // heads: 32 kc x 512 cols x 8 (key|erase|add|beta|pad)
#define H_TOTAL 475136
#define B_BA   0        // [512] b_ih+b_hh (r,z)
#define B_BNI  512      // [256]
#define B_BNH  768      // [256]
#define B_BH   1024     // [512]
#define B_TOTAL 1536
#define WS_BYTES (H_TOTAL * 2 + B_TOTAL * 4)

// persistent weight-register depths: these chunks are loop-invariant and
// live in VGPRs for the whole kernel. (16+8+8)*4 = 128 VGPRs persistent.
// LDS (149 KB) caps us at 1 WG/CU = 2 waves/SIMD, so up to 256 VGPRs is
// occupancy-free. launch_bounds min-waves arg MUST be 1: round-4 evidence
// shows (512,2) capped the allocator at 128 regs -> 28 GB scratch spill.
#define PFA 16
#define PFX 8
#define PFH 8

typedef _Float16 h2 __attribute__((ext_vector_type(2)));
typedef _Float16 h8 __attribute__((ext_vector_type(8)));
union H8 { h8 v; h2 d[4]; };

__device__ __forceinline__ float sigf(float x) { return 1.0f / (1.0f + expf(-x)); }
__device__ __forceinline__ float softplusf(float x) {
    return (x > 15.0f) ? x : log1pf(expf(x));
}
__device__ __forceinline__ float fdot2(h2 a, h2 b, float c) {
#if __has_builtin(__builtin_amdgcn_fdot2)
    return __builtin_amdgcn_fdot2(a, b, c, false);
#else
    return fmaf((float)a[0], (float)b[0], fmaf((float)a[1], (float)b[1], c));
#endif
}

// lgkm-only barrier: orders LDS traffic without draining vmcnt, so global
// loads stay in flight across phase boundaries. All in-loop inter-thread
// communication is via LDS; the compiler inserts per-value vmcnt waits for
// each thread's own global loads.
__device__ __forceinline__ void barL() {
    asm volatile("s_waitcnt lgkmcnt(0)\n\ts_barrier" ::: "memory");
}

__global__ __launch_bounds__(256) void prep_kernel(
    const float* __restrict__ Wih, const float* __restrict__ bih,
    const float* __restrict__ Whh, const float* __restrict__ bhh,
    const float* __restrict__ Wkey, const float* __restrict__ bkey,
    const float* __restrict__ Wbeta, const float* __restrict__ bbeta,
    const float* __restrict__ Wer, const float* __restrict__ ber,
    const float* __restrict__ Wadd, const float* __restrict__ badd,
    _Float16* __restrict__ wsH, float* __restrict__ wsB)
{
    int i = blockIdx.x * 256 + threadIdx.x;
    if (i < H_TOTAL) {
        float v;
        if (i < H_WNI) {                       // rz [kc][512][8]
            int ch = i >> 3, e = i & 7;
            int kc = ch >> 9, col = ch & 511;
            int k = kc * 8 + e;
            v = (k < 192) ? Wih[col * 192 + k] : Whh[col * 256 + (k - 192)];
        } else if (i < H_WNH) {                // inn [kc][256][8], k<192
            int i2 = i - H_WNI; int ch = i2 >> 3, e = i2 & 7;
            int kc = ch >> 8, col = ch & 255;
            v = Wih[(512 + col) * 192 + kc * 8 + e];
        } else if (i < H_WH) {                 // hn [kc][256][8], k<256
            int i2 = i - H_WNH; int ch = i2 >> 3, e = i2 & 7;
            int kc = ch >> 8, col = ch & 255;
            v = Whh[(512 + col) * 256 + kc * 8 + e];
        } else {                               // heads [kc][512][8], k<256
            int i2 = i - H_WH; int ch = i2 >> 3, e = i2 & 7;
            int kc = ch >> 9, col = ch & 511;
            int k = kc * 8 + e;
            if (col < 128)       v = Wkey[col * 256 + k];
            else if (col < 256)  v = Wer[(col - 128) * 256 + k];
            else if (col < 384)  v = Wadd[(col - 256) * 256 + k];
            else if (col == 384) v = Wbeta[k];
            else                 v = 0.0f;
        }
        wsH[i] = (_Float16)v;
    } else if (i < H_TOTAL + B_TOTAL) {
        int j = i - H_TOTAL;
        float v;
        if (j < 512)        v = bih[j] + bhh[j];
        else if (j < 768)   v = bih[512 + (j - 512)];
        else if (j < 1024)  v = bhh[512 + (j - 768)];
        else {
            int c = j - 1024;
            if (c < 128)       v = bkey[c];
            else if (c < 256)  v = ber[c - 128];
            else if (c < 384)  v = badd[c - 256];
            else if (c == 384) v = bbeta[0];
            else               v = 0.0f;
        }
        wsB[j] = v;
    }
}

// Slow-path memory module (verified): __syncthreads-based.
__device__ __forceinline__ void memory_step(
    int u, bool wr, float (*M)[NWORD + 1],
    const float* keyv, const float* ev, const float* av,
    float* cosb, float* wb, float* part, float* readv, float* scal)
{
    if (u < 64) {                       // ||k||
        float s = keyv[u] * keyv[u] + keyv[u + 64] * keyv[u + 64];
        #pragma unroll
        for (int o = 32; o >= 1; o >>= 1) s += __shfl_xor(s, o);
        if (u == 0) scal[0] = 1.0f / (sqrtf(s) + EPSF);
    }
    __syncthreads();
    {                                      // cosine sim: 2 threads / row
        int rr = u >> 1, hh = u & 1;
        const float* Mr = &M[rr][hh * 64];
        const float4* kk4 = (const float4*)(keyv + hh * 64);
        float s2 = 0.f, sc = 0.f;
        #pragma unroll
        for (int p = 0; p < 16; ++p) {
            float4 k4 = kk4[p];
            float m0 = Mr[4 * p], m1 = Mr[4 * p + 1], m2 = Mr[4 * p + 2], m3 = Mr[4 * p + 3];
            s2 = fmaf(m0, m0, s2); sc = fmaf(m0, k4.x, sc);
            s2 = fmaf(m1, m1, s2); sc = fmaf(m1, k4.y, sc);
            s2 = fmaf(m2, m2, s2); sc = fmaf(m2, k4.z, sc);
            s2 = fmaf(m3, m3, s2); sc = fmaf(m3, k4.w, sc);
        }
        s2 += __shfl_xor(s2, 1);
        sc += __shfl_xor(sc, 1);
        if (hh == 0) cosb[rr] = sc * scal[0] / (sqrtf(s2) + EPSF);
    }
    __syncthreads();
    if (u < 64) {                       // softmax over 128 logits
        float beta = scal[1];
        float l0 = beta * cosb[u], l1 = beta * cosb[u + 64];
        float mx = fmaxf(l0, l1);
        #pragma unroll
        for (int o = 32; o >= 1; o >>= 1) mx = fmaxf(mx, __shfl_xor(mx, o));
        float e0 = expf(l0 - mx), e1 = expf(l1 - mx);
        float s = e0 + e1;
        #pragma unroll
        for (int o = 32; o >= 1; o >>= 1) s += __shfl_xor(s, o);
        float inv = 1.0f / s;
        wb[u] = e0 * inv;
        wb[u + 64] = e1 * inv;
    }
    __syncthreads();
    {   // FUSED read+update
        int j = u & 127, rh = u >> 7;
        float ej = ev[j], aj = av[j];
        const float4* wb4 = (const float4*)(wb + rh * 64);
        float p = 0.f;
        #pragma unroll
        for (int pq = 0; pq < 16; ++pq) {
            float4 w4 = wb4[pq];
            int r = rh * 64 + 4 * pq;
            float m0 = M[r][j], m1 = M[r + 1][j], m2 = M[r + 2][j], m3 = M[r + 3][j];
            p = fmaf(w4.x, m0, p);
            p = fmaf(w4.y, m1, p);
            p = fmaf(w4.z, m2, p);
            p = fmaf(w4.w, m3, p);
            if (wr) {
                M[r][j]     = fmaf(-w4.x, fmaf(ej, m0, -aj), m0);
                M[r + 1][j] = fmaf(-w4.y, fmaf(ej, m1, -aj), m1);
                M[r + 2][j] = fmaf(-w4.z, fmaf(ej, m2, -aj), m2);
                M[r + 3][j] = fmaf(-w4.w, fmaf(ej, m3, -aj), m3);
            }
        }
        part[rh * 128 + j] = p;
    }
    __syncthreads();
    if (wr && u < 128) readv[u] = part[u] + part[128 + u];
}

#define DOT_RZ(WSRC) do { H8 w_; w_.v = (WSRC); \
    a0 = fdot2(x0.d[0], w_.d[0], a0); c0 = fdot2(x0.d[1], w_.d[1], c0); \
    a0 = fdot2(x0.d[2], w_.d[2], a0); c0 = fdot2(x0.d[3], w_.d[3], c0); \
    a1 = fdot2(x1.d[0], w_.d[0], a1); c1 = fdot2(x1.d[1], w_.d[1], c1); \
    a1 = fdot2(x1.d[2], w_.d[2], a1); c1 = fdot2(x1.d[3], w_.d[3], c1); } while (0)

#define DOT_AUX(WSRC) do { H8 w_; w_.v = (WSRC); \
    e0 = fdot2(x0.d[0], w_.d[0], e0); f0 = fdot2(x0.d[1], w_.d[1], f0); \
    e0 = fdot2(x0.d[2], w_.d[2], e0); f0 = fdot2(x0.d[3], w_.d[3], f0); \
    e1 = fdot2(x1.d[0], w_.d[0], e1); f1 = fdot2(x1.d[1], w_.d[1], f1); \
    e1 = fdot2(x1.d[2], w_.d[2], e1); f1 = fdot2(x1.d[3], w_.d[3], f1); } while (0)

#define DOT_HD(WSRC) do { H8 w_; w_.v = (WSRC); \
    h0 = fdot2(x0.d[0], w_.d[0], h0); d0 = fdot2(x0.d[1], w_.d[1], d0); \
    h0 = fdot2(x0.d[2], w_.d[2], h0); d0 = fdot2(x0.d[3], w_.d[3], d0); \
    h1 = fdot2(x1.d[0], w_.d[0], h1); d1 = fdot2(x1.d[1], w_.d[1], d1); \
    h1 = fdot2(x1.d[2], w_.d[2], h1); d1 = fdot2(x1.d[3], w_.d[3], d1); } while (0)

#define LOADX(KC) H8 x0; x0.v = A0[KC]; H8 x1; x1.v = A1[KC]

// 2 rows / 512-thread block (shared weight loads) + lgkm-only barriers +
// PERSISTENT weight registers: the first 16 rz chunks, 8 aux chunks and
// 8 head chunks per thread are loop-invariant, loaded once in the prologue
// and held in VGPRs for the whole kernel (zero per-step L2 traffic for
// them: 950 -> ~754 KB/block-step). LDS ~149 KB -> 1 WG/CU, 2 waves/SIMD,
// so up to 256 VGPRs is occupancy-free.
__global__ __launch_bounds__(512, 1) void ntm_fast4(
    const float* __restrict__ data, const int* __restrict__ batch_sizes,
    const int* __restrict__ unsort, const float* __restrict__ M0,
    const _Float16* __restrict__ wsH, const float* __restrict__ wsB,
    float* __restrict__ out)
{
    __shared__ float M[2][NMEM][NWORD + 1];               // 132096 B
    __shared__ __align__(16) _Float16 actH[2][NACT];      // 1792 B
    __shared__ float ctrlB[2][NCTRL];
    __shared__ float gA[2][512];
    __shared__ float iA[2][NCTRL];
    __shared__ float hA[2][NCTRL];
    __shared__ __align__(16) float readv[2][NWORD], keyv[2][NWORD], ev[2][NWORD], av[2][NWORD];
    __shared__ __align__(16) float cosb[2][NMEM], wb[2][NMEM], part[2][2 * NWORD];
    __shared__ float kn2[2][2], betav[2];
    __shared__ int len_sh[2], gpos[2];

    const int t = threadIdx.x;
    const int q = t >> 8;          // row half (0/1)
    const int u = t & 255;         // local tid within half
    const int g = blockIdx.x;
    const int b = 2 * g + q;       // this half's packed row

    if (t < 2) {
        int bb = 2 * g + t;
        int L = 0;
        for (int s = 0; s < NT; ++s) L += (batch_sizes[s] > bb);
        len_sh[t] = L;
    }
    {   // inverse permutation: find out-position of each packed row
        int ug = unsort[t];                 // t in [0,512) == NB
        if (ug == 2 * g)     gpos[0] = t;
        if (ug == 2 * g + 1) gpos[1] = t;
    }
    for (int i = t; i < 2 * NMEM * NWORD; i += 512) {
        int ii = i & (NMEM * NWORD - 1);
        M[i >> 14][ii >> 7][ii & 127] = M0[ii];
    }
    ctrlB[q][u] = 0.0f;
    actH[q][192 + u] = (_Float16)0.0f;
    if (u < NWORD) readv[q][u] = 0.0f;
    __syncthreads();
    const int len0 = len_sh[0], len1 = len_sh[1];   // len0 >= len1 (packed order)

    const float bRZ  = wsB[B_BA + t];
    const float bAux = (t < 256) ? wsB[B_BNI + u] : wsB[B_BNH + u];
    const float bHD  = wsB[B_BH + t];

    const h8* __restrict__ pA  = (const h8*)(wsH + H_WA);
    const h8* __restrict__ pI  = (const h8*)(wsH + H_WNI);
    const h8* __restrict__ pH  = (const h8*)(wsH + H_WNH);
    const h8* __restrict__ pHD = (const h8*)(wsH + H_WH);
    const h8* A0 = (const h8*)actH[0];
    const h8* A1 = (const h8*)actH[1];

    // ---- persistent weight registers (loop-invariant)
    h8 pfA[PFA];
    h8 pfX[PFX];
    h8 pfHd[PFH];
    #pragma unroll
    for (int i = 0; i < PFA; ++i) pfA[i] = pA[i * 512 + t];
    if (t < 256) {
        #pragma unroll
        for (int i = 0; i < PFX; ++i) pfX[i] = pI[i * 256 + u];
    } else {
        #pragma unroll
        for (int i = 0; i < PFX; ++i) pfX[i] = pH[i * 256 + u];
    }
    #pragma unroll
    for (int i = 0; i < PFH; ++i) pfHd[i] = pHD[i * 512 + t];

    float xf = 0.0f;
    if (u >= 128 && u < 192) xf = data[((long)0 * NB + b) * NDIN + (u - 128)];

    for (int ts = 0; ts < len0; ++ts) {
        const bool wr = (q == 0) | (ts < len1);
        // ---- stage activations as fp16 (state masters stay fp32)
        if (u < 128)      actH[q][64 + u] = (_Float16)readv[q][u];
        else if (u < 192) actH[q][u - 128] = (_Float16)xf;
        barL();

        // ---- fused sweep: rz col t (both rows) + aux col u
        float a0 = bRZ, c0 = 0.f, a1 = bRZ, c1 = 0.f;
        float e0 = bAux, f0 = 0.f, e1 = bAux, f1 = 0.f;
        if (t < 256) {
            #pragma unroll
            for (int kc = 0; kc < PFX; ++kc) {          // persistent w + wn
                LOADX(kc);
                DOT_RZ(pfA[kc]); DOT_AUX(pfX[kc]);
            }
            #pragma unroll
            for (int kc = PFX; kc < PFA; ++kc) {        // persistent w
                LOADX(kc);
                DOT_RZ(pfA[kc]); DOT_AUX(pI[kc * 256 + u]);
            }
            #pragma unroll
            for (int kc = PFA; kc < 24; ++kc) {
                LOADX(kc);
                DOT_RZ(pA[kc * 512 + t]); DOT_AUX(pI[kc * 256 + u]);
            }
            #pragma unroll 4
            for (int kc = 24; kc < 56; ++kc) {          // rz only
                LOADX(kc);
                DOT_RZ(pA[kc * 512 + t]);
            }
        } else {
            #pragma unroll
            for (int kc = 0; kc < PFA; ++kc) {          // persistent w
                LOADX(kc);
                DOT_RZ(pfA[kc]);
            }
            #pragma unroll
            for (int kc = PFA; kc < 24; ++kc) {
                LOADX(kc);
                DOT_RZ(pA[kc * 512 + t]);
            }
            #pragma unroll
            for (int kc = 24; kc < 24 + PFX; ++kc) {    // persistent wn
                LOADX(kc);
                DOT_RZ(pA[kc * 512 + t]); DOT_AUX(pfX[kc - 24]);
            }
            #pragma unroll 4
            for (int kc = 24 + PFX; kc < 56; ++kc) {
                LOADX(kc);
                DOT_RZ(pA[kc * 512 + t]); DOT_AUX(pH[(kc - 24) * 256 + u]);
            }
        }
        gA[0][t] = a0 + c0;
        gA[1][t] = a1 + c1;
        if (t < 256) { iA[0][u] = e0 + f0; iA[1][u] = e1 + f1; }
        else         { hA[0][u] = e0 + f0; hA[1][u] = e1 + f1; }
        barL();

        {   // gate combine: thread (q,u) owns ctrl element u of row q
            float rg = sigf(gA[q][u]);
            float zg = sigf(gA[q][NCTRL + u]);
            float ng = tanhf(fmaf(rg, hA[q][u], iA[q][u]));
            float cold = ctrlB[q][u];
            float cnew = fmaf(zg, cold - ng, ng);
            if (wr) {
                ctrlB[q][u] = cnew;
                actH[q][192 + u] = (_Float16)cnew;
            }
        }
        barL();

        // ---- heads: col t for both rows, 32 chunks over new ctrl
        float h0 = bHD, d0 = 0.f, h1 = bHD, d1 = 0.f;
        #pragma unroll
        for (int kc = 0; kc < PFH; ++kc) {
            LOADX(24 + kc);
            DOT_HD(pfHd[kc]);
        }
        #pragma unroll 4
        for (int kc = PFH; kc < 32; ++kc) {
            LOADX(24 + kc);
            DOT_HD(pHD[kc * 512 + t]);
        }
        h0 += d0; h1 += d1;
        if (t < 128) {
            float k0 = tanhf(h0), k1 = tanhf(h1);
            keyv[0][t] = k0; keyv[1][t] = k1;
            // fold ||k||^2 into this phase: per-wave butterfly, 2 partials/row
            float s0 = k0 * k0, s1 = k1 * k1;
            #pragma unroll
            for (int o = 32; o >= 1; o >>= 1) {
                s0 += __shfl_xor(s0, o);
                s1 += __shfl_xor(s1, o);
            }
            if ((t & 63) == 0) { kn2[0][t >> 6] = s0; kn2[1][t >> 6] = s1; }
        }
        else if (t < 256)  { ev[0][t - 128] = sigf(h0); ev[1][t - 128] = sigf(h1); }
        else if (t < 384)  { av[0][t - 256] = h0;       av[1][t - 256] = h1; }
        else if (t == 384) { betav[0] = softplusf(h0);  betav[1] = softplusf(h1); }
        barL();

        // ---- memory: cosine sim (2 threads / mem-row)
        {
            float invk = 1.0f / (sqrtf(kn2[q][0] + kn2[q][1]) + EPSF);
            int rr = u >> 1, hh = u & 1;
            const float* Mr = &M[q][rr][hh * 64];
            const float4* kk4 = (const float4*)(&keyv[q][hh * 64]);
            float s2 = 0.f, sc = 0.f;
            #pragma unroll
            for (int p = 0; p < 16; ++p) {
                float4 k4 = kk4[p];
                float m0 = Mr[4 * p], m1 = Mr[4 * p + 1], m2 = Mr[4 * p + 2], m3 = Mr[4 * p + 3];
                s2 = fmaf(m0, m0, s2); sc = fmaf(m0, k4.x, sc);
                s2 = fmaf(m1, m1, s2); sc = fmaf(m1, k4.y, sc);
                s2 = fmaf(m2, m2, s2); sc = fmaf(m2, k4.z, sc);
                s2 = fmaf(m3, m3, s2); sc = fmaf(m3, k4.w, sc);
            }
            s2 += __shfl_xor(s2, 1);
            sc += __shfl_xor(sc, 1);
            if (hh == 0) cosb[q][rr] = sc * invk / (sqrtf(s2) + EPSF);
        }
        barL();

        // ---- softmax over 128 logits (64 threads per half)
        if (u < 64) {
            float beta = betav[q];
            float l0 = beta * cosb[q][u], l1 = beta * cosb[q][u + 64];
            float mx = fmaxf(l0, l1);
            #pragma unroll
            for (int o = 32; o >= 1; o >>= 1) mx = fmaxf(mx, __shfl_xor(mx, o));
            float se0 = expf(l0 - mx), se1 = expf(l1 - mx);
            float s = se0 + se1;
            #pragma unroll
            for (int o = 32; o >= 1; o >>= 1) s += __shfl_xor(s, o);
            float inv = 1.0f / s;
            wb[q][u] = se0 * inv;
            wb[q][u + 64] = se1 * inv;
        }
        // prefetch next step's x; delivery overlaps softmax + fused M phase
        {
            int tn = (ts + 1 < NT) ? (ts + 1) : 0;
            if (u >= 128 && u < 192) xf = data[((long)tn * NB + b) * NDIN + (u - 128)];
        }
        barL();

        // ---- FUSED read+update
        {
            int j = u & 127, rh = u >> 7;
            float ej = ev[q][j], aj = av[q][j];
            const float4* wb4 = (const float4*)(&wb[q][rh * 64]);
            float p = 0.f;
            #pragma unroll
            for (int pq = 0; pq < 16; ++pq) {
                float4 w4 = wb4[pq];
                int r = rh * 64 + 4 * pq;
                float m0 = M[q][r][j], m1 = M[q][r + 1][j], m2 = M[q][r + 2][j], m3 = M[q][r + 3][j];
                p = fmaf(w4.x, m0, p);
                p = fmaf(w4.y, m1, p);
                p = fmaf(w4.z, m2, p);
                p = fmaf(w4.w, m3, p);
                if (wr) {
                    M[q][r][j]     = fmaf(-w4.x, fmaf(ej, m0, -aj), m0);
                    M[q][r + 1][j] = fmaf(-w4.y, fmaf(ej, m1, -aj), m1);
                    M[q][r + 2][j] = fmaf(-w4.z, fmaf(ej, m2, -aj), m2);
                    M[q][r + 3][j] = fmaf(-w4.w, fmaf(ej, m3, -aj), m3);
                }
            }
            part[q][rh * 128 + j] = p;
        }
        barL();
        if (wr && u < 128) readv[q][u] = part[q][u] + part[q][128 + u];
        // readv[u] produced and consumed by thread u -> no barrier here
    }

    out[gpos[q] * NCTRL + u] = ctrlB[q][u];
    if (u < NWORD) out[NB * NCTRL + gpos[q] * NWORD + u] = readv[q][u];
}

// FALLBACK (ws too small): verified slow path.
__global__ __launch_bounds__(256) void ntm_slow(
    const float* __restrict__ data, const int* __restrict__ batch_sizes,
    const int* __restrict__ unsort,
    const float* __restrict__ Wih, const float* __restrict__ bih,
    const float* __restrict__ Whh, const float* __restrict__ bhh,
    const float* __restrict__ Wkey, const float* __restrict__ bkey,
    const float* __restrict__ Wbeta, const float* __restrict__ bbeta,
    const float* __restrict__ Wer, const float* __restrict__ ber,
    const float* __restrict__ Wadd, const float* __restrict__ badd,
    const float* __restrict__ M0, float* __restrict__ out)
{
    __shared__ float M[NMEM][NWORD + 1];
    __shared__ float act[NACT];
    __shared__ float ctrlB[NCTRL];
    __shared__ float gpre[512], ginn[256], ghn[256], hpre[448];
    __shared__ __align__(16) float readv[NWORD], keyv[NWORD], ev[NWORD], av[NWORD];
    __shared__ __align__(16) float cosb[NMEM], wb[NMEM], part[2 * NWORD], scal[2];
    __shared__ int len_sh;

    const int tid = threadIdx.x;
    const int g = blockIdx.x;
    const int b = unsort[g];

    if (tid == 0) {
        int L = 0;
        for (int t = 0; t < NT; ++t) L += (batch_sizes[t] > b);
        len_sh = L;
    }
    for (int i = tid; i < NMEM * NWORD; i += 256)
        M[i >> 7][i & 127] = M0[i];
    ctrlB[tid] = 0.0f;
    if (tid < NWORD) readv[tid] = 0.0f;
    __syncthreads();
    const int len = len_sh;
    const int wave = tid >> 6, lane = tid & 63;

    for (int t = 0; t < len; ++t) {
        if (tid < 64)  act[tid] = data[((long)t * NB + b) * NDIN + tid];
        if (tid < 128) act[64 + tid] = readv[tid];
        act[192 + tid] = ctrlB[tid];
        __syncthreads();

        for (int j = wave; j < 512; j += 4) {
            float p = 0.f;
            for (int k = lane; k < 192; k += 64) p = fmaf(act[k], Wih[j * 192 + k], p);
            for (int k = lane; k < 256; k += 64) p = fmaf(act[192 + k], Whh[j * 256 + k], p);
            #pragma unroll
            for (int o = 32; o >= 1; o >>= 1) p += __shfl_xor(p, o);
            if (lane == 0) gpre[j] = p;
        }
        for (int j = wave; j < 256; j += 4) {
            float pi = 0.f, ph = 0.f;
            for (int k = lane; k < 192; k += 64) pi = fmaf(act[k], Wih[(512 + j) * 192 + k], pi);
            for (int k = lane; k < 256; k += 64) ph = fmaf(act[192 + k], Whh[(512 + j) * 256 + k], ph);
            #pragma unroll
            for (int o = 32; o >= 1; o >>= 1) { pi += __shfl_xor(pi, o); ph += __shfl_xor(ph, o); }
            if (lane == 0) { ginn[j] = pi; ghn[j] = ph; }
        }
        __syncthreads();
        {
            float r = sigf(gpre[tid] + bih[tid] + bhh[tid]);
            float z = sigf(gpre[256 + tid] + bih[256 + tid] + bhh[256 + tid]);
            float inn = ginn[tid] + bih[512 + tid];
            float hn  = ghn[tid] + bhh[512 + tid];
            float n = tanhf(fmaf(r, hn, inn));
            float cold = act[192 + tid];
            ctrlB[tid] = fmaf(z, cold - n, n);
        }
        __syncthreads();
        for (int j = wave; j < 385; j += 4) {
            const float* Wp; long base;
            if (j < 128)      { Wp = Wkey;  base = (long)j * 256; }
            else if (j < 256) { Wp = Wer;   base = (long)(j - 128) * 256; }
            else if (j < 384) { Wp = Wadd;  base = (long)(j - 256) * 256; }
            else              { Wp = Wbeta; base = 0; }
            float p = 0.f;
            for (int k = lane; k < 256; k += 64) p = fmaf(ctrlB[k], Wp[base + k], p);
            #pragma unroll
            for (int o = 32; o >= 1; o >>= 1) p += __shfl_xor(p, o);
            if (lane == 0) hpre[j] = p;
        }
        __syncthreads();
        if (tid < 128) {
            keyv[tid] = tanhf(hpre[tid] + bkey[tid]);
            ev[tid]   = sigf(hpre[128 + tid] + ber[tid]);
            av[tid]   = hpre[256 + tid] + badd[tid];
        }
        if (tid == 0) scal[1] = softplusf(hpre[384] + bbeta[0]);
        __syncthreads();

        memory_step(tid, true, M, keyv, ev, av, cosb, wb, part, readv, scal);
        __syncthreads();
    }

    out[g * NCTRL + tid] = ctrlB[tid];
    if (tid < NWORD) out[NB * NCTRL + g * NWORD + tid] = readv[tid];
}

extern "C" void kernel_launch(void* const* d_in, const int* in_sizes, int n_in,
                              void* d_out, int out_size, void* d_ws, size_t ws_size,
                              hipStream_t stream)
{
    const float* data       = (const float*)d_in[0];
    const int*  batch_sizes = (const int*)d_in[1];
    const int*  unsort      = (const int*)d_in[2];
    float* out = (float*)d_out;

    if (ws_size >= (size_t)WS_BYTES) {
        _Float16* wsH = (_Float16*)d_ws;
        float* wsB = (float*)((char*)d_ws + (size_t)H_TOTAL * 2);
        prep_kernel<<<(H_TOTAL + B_TOTAL + 255) / 256, 256, 0, stream>>>(
            (const float*)d_in[3], (const float*)d_in[4], (const float*)d_in[5],
            (const float*)d_in[6], (const float*)d_in[7], (const float*)d_in[8],
            (const float*)d_in[9], (const float*)d_in[10], (const float*)d_in[11],
            (const float*)d_in[12], (const float*)d_in[13], (const float*)d_in[14],
            wsH, wsB);
        ntm_fast4<<<NB / 2, 512, 0, stream>>>(data, batch_sizes, unsort,
                                              (const float*)d_in[15], wsH, wsB, out);
    } else {
        ntm_slow<<<NB, 256, 0, stream>>>(
            data, batch_sizes, unsort,
            (const float*)d_in[3], (const float*)d_in[4], (const float*)d_in[5],
            (const float*)d_in[6], (const float*)d_in[7], (const float*)d_in[8],
            (const float*)d_in[9], (const float*)d_in[10], (const float*)d_in[11],
            (const float*)d_in[12], (const float*)d_in[13], (const float*)d_in[14],
            (const float*)d_in[15], out);
    }
}

// Round 7
// 16563.075 us; speedup vs baseline: 1.2995x; 1.2153x over previous
//
#include <hip/hip_runtime.h>
#include <math.h>

#define NB 512      // batch
#define NT 512      // time
#define NCTRL 256
#define NWORD 128
#define NMEM 128
#define NDIN 64
#define NACT 448    // x(64) | read(128) | ctrl(256)
#define EPSF 1e-6f

// fp16 weight panel, CHUNK-TRANSPOSED layout (identical to prior rounds):
//   element(region, kc, col, e) at region_base + (kc*NCOLS + col)*8 + e
#define H_WA   0        // rz:    56 kc x 512 cols x 8
#define H_WNI  229376   // inn:   24 kc x 256 cols x 8
#define H_WNH  278528   // hn:    32 kc x 256 cols x 8
#define H_WH   344064   // heads: 32 kc x 512 cols x 8 (key|erase|add|beta|pad)
#define H_TOTAL 475136
#define B_BA   0        // [512] b_ih+b_hh (r,z)
#define B_BNI  512      // [256]
#define B_BNH  768      // [256]
#define B_BH   1024     // [512]
#define B_TOTAL 1536
#define WS_BYTES (H_TOTAL * 2 + B_TOTAL * 4)

typedef _Float16 h2 __attribute__((ext_vector_type(2)));
typedef _Float16 h8 __attribute__((ext_vector_type(8)));
union H8 { h8 v; h2 d[4]; };

__device__ __forceinline__ float sigf(float x) { return 1.0f / (1.0f + expf(-x)); }
__device__ __forceinline__ float softplusf(float x) {
    return (x > 15.0f) ? x : log1pf(expf(x));
}
__device__ __forceinline__ float fdot2(h2 a, h2 b, float c) {
#if __has_builtin(__builtin_amdgcn_fdot2)
    return __builtin_amdgcn_fdot2(a, b, c, false);
#else
    return fmaf((float)a[0], (float)b[0], fmaf((float)a[1], (float)b[1], c));
#endif
}

__global__ __launch_bounds__(256) void prep_kernel(
    const float* __restrict__ Wih, const float* __restrict__ bih,
    const float* __restrict__ Whh, const float* __restrict__ bhh,
    const float* __restrict__ Wkey, const float* __restrict__ bkey,
    const float* __restrict__ Wbeta, const float* __restrict__ bbeta,
    const float* __restrict__ Wer, const float* __restrict__ ber,
    const float* __restrict__ Wadd, const float* __restrict__ badd,
    _Float16* __restrict__ wsH, float* __restrict__ wsB)
{
    int i = blockIdx.x * 256 + threadIdx.x;
    if (i < H_TOTAL) {
        float v;
        if (i < H_WNI) {                       // rz [kc][512][8]
            int ch = i >> 3, e = i & 7;
            int kc = ch >> 9, col = ch & 511;
            int k = kc * 8 + e;
            v = (k < 192) ? Wih[col * 192 + k] : Whh[col * 256 + (k - 192)];
        } else if (i < H_WNH) {                // inn [kc][256][8], k<192
            int i2 = i - H_WNI; int ch = i2 >> 3, e = i2 & 7;
            int kc = ch >> 8, col = ch & 255;
            v = Wih[(512 + col) * 192 + kc * 8 + e];
        } else if (i < H_WH) {                 // hn [kc][256][8], k<256
            int i2 = i - H_WNH; int ch = i2 >> 3, e = i2 & 7;
            int kc = ch >> 8, col = ch & 255;
            v = Whh[(512 + col) * 256 + kc * 8 + e];
        } else {                               // heads [kc][512][8], k<256
            int i2 = i - H_WH; int ch = i2 >> 3, e = i2 & 7;
            int kc = ch >> 9, col = ch & 511;
            int k = kc * 8 + e;
            if (col < 128)       v = Wkey[col * 256 + k];
            else if (col < 256)  v = Wer[(col - 128) * 256 + k];
            else if (col < 384)  v = Wadd[(col - 256) * 256 + k];
            else if (col == 384) v = Wbeta[k];
            else                 v = 0.0f;
        }
        wsH[i] = (_Float16)v;
    } else if (i < H_TOTAL + B_TOTAL) {
        int j = i - H_TOTAL;
        float v;
        if (j < 512)        v = bih[j] + bhh[j];
        else if (j < 768)   v = bih[512 + (j - 512)];
        else if (j < 1024)  v = bhh[512 + (j - 768)];
        else {
            int c = j - 1024;
            if (c < 128)       v = bkey[c];
            else if (c < 256)  v = ber[c - 128];
            else if (c < 384)  v = badd[c - 256];
            else if (c == 384) v = bbeta[0];
            else               v = 0.0f;
        }
        wsB[j] = v;
    }
}

// Verified memory module (used by slow path only).
__device__ __forceinline__ void memory_step(
    int u, bool wr, float (*M)[NWORD + 1],
    const float* keyv, const float* ev, const float* av,
    float* cosb, float* wb, float* part, float* readv, float* scal)
{
    if (u < 64) {                       // ||k||
        float s = keyv[u] * keyv[u] + keyv[u + 64] * keyv[u + 64];
        #pragma unroll
        for (int o = 32; o >= 1; o >>= 1) s += __shfl_xor(s, o);
        if (u == 0) scal[0] = 1.0f / (sqrtf(s) + EPSF);
    }
    __syncthreads();
    {                                      // cosine sim: 2 threads / row
        int rr = u >> 1, hh = u & 1;
        const float* Mr = &M[rr][hh * 64];
        const float4* kk4 = (const float4*)(keyv + hh * 64);
        float s2 = 0.f, sc = 0.f;
        #pragma unroll
        for (int p = 0; p < 16; ++p) {
            float4 k4 = kk4[p];
            float m0 = Mr[4 * p], m1 = Mr[4 * p + 1], m2 = Mr[4 * p + 2], m3 = Mr[4 * p + 3];
            s2 = fmaf(m0, m0, s2); sc = fmaf(m0, k4.x, sc);
            s2 = fmaf(m1, m1, s2); sc = fmaf(m1, k4.y, sc);
            s2 = fmaf(m2, m2, s2); sc = fmaf(m2, k4.z, sc);
            s2 = fmaf(m3, m3, s2); sc = fmaf(m3, k4.w, sc);
        }
        s2 += __shfl_xor(s2, 1);
        sc += __shfl_xor(sc, 1);
        if (hh == 0) cosb[rr] = sc * scal[0] / (sqrtf(s2) + EPSF);
    }
    __syncthreads();
    if (u < 64) {                       // softmax over 128 logits
        float beta = scal[1];
        float l0 = beta * cosb[u], l1 = beta * cosb[u + 64];
        float mx = fmaxf(l0, l1);
        #pragma unroll
        for (int o = 32; o >= 1; o >>= 1) mx = fmaxf(mx, __shfl_xor(mx, o));
        float e0 = expf(l0 - mx), e1 = expf(l1 - mx);
        float s = e0 + e1;
        #pragma unroll
        for (int o = 32; o >= 1; o >>= 1) s += __shfl_xor(s, o);
        float inv = 1.0f / s;
        wb[u] = e0 * inv;
        wb[u + 64] = e1 * inv;
    }
    __syncthreads();
    {   // FUSED read+update
        int j = u & 127, rh = u >> 7;
        float ej = ev[j], aj = av[j];
        const float4* wb4 = (const float4*)(wb + rh * 64);
        float p = 0.f;
        #pragma unroll
        for (int pq = 0; pq < 16; ++pq) {
            float4 w4 = wb4[pq];
            int r = rh * 64 + 4 * pq;
            float m0 = M[r][j], m1 = M[r + 1][j], m2 = M[r + 2][j], m3 = M[r + 3][j];
            p = fmaf(w4.x, m0, p);
            p = fmaf(w4.y, m1, p);
            p = fmaf(w4.z, m2, p);
            p = fmaf(w4.w, m3, p);
            if (wr) {
                M[r][j]     = fmaf(-w4.x, fmaf(ej, m0, -aj), m0);
                M[r + 1][j] = fmaf(-w4.y, fmaf(ej, m1, -aj), m1);
                M[r + 2][j] = fmaf(-w4.z, fmaf(ej, m2, -aj), m2);
                M[r + 3][j] = fmaf(-w4.w, fmaf(ej, m3, -aj), m3);
            }
        }
        part[rh * 128 + j] = p;
    }
    __syncthreads();
    if (wr && u < 128) readv[u] = part[u] + part[128 + u];
}

// one weight chunk dotted against both rows' activations (8 fdot2)
#define DOT2R(WSRC) do { H8 w_; w_.v = (WSRC); \
    a0 = fdot2(x0.d[0], w_.d[0], a0); c0 = fdot2(x0.d[1], w_.d[1], c0); \
    a0 = fdot2(x0.d[2], w_.d[2], a0); c0 = fdot2(x0.d[3], w_.d[3], c0); \
    a1 = fdot2(x1.d[0], w_.d[0], a1); c1 = fdot2(x1.d[1], w_.d[1], c1); \
    a1 = fdot2(x1.d[2], w_.d[2], a1); c1 = fdot2(x1.d[3], w_.d[3], c1); } while (0)

#define LOADX(KC) H8 x0; x0.v = A0[KC]; H8 x1; x1.v = A1[KC]

// 2 rows per 1024-thread block. Same weight sharing as the verified round-2
// kernel (each panel chunk loaded from L2 exactly once per block-step), but
// 16 waves/CU instead of 8: round-2 measured only 28 B/cy per-CU L2
// delivery (~50% of the ~56 B/cy port share) -> latency/TLP-limited.
// Column c's k-range is split across lane pair (2c, 2c+1); the two halves
// combine with one __shfl_xor(.,1). Memory module keeps the verified
// 256-threads-per-row mapping on t<512; t>=512 only hit the barriers.
// LDS ~149 KB -> 1 WG/CU; VGPR must be <=128 for 4 waves/SIMD (per-thread
// pressure is LOWER than round-2's 96).
__global__ __launch_bounds__(1024) void ntm_fast5(
    const float* __restrict__ data, const int* __restrict__ batch_sizes,
    const int* __restrict__ unsort, const float* __restrict__ M0,
    const _Float16* __restrict__ wsH, const float* __restrict__ wsB,
    float* __restrict__ out)
{
    __shared__ float M[2][NMEM][NWORD + 1];               // 132096 B
    __shared__ __align__(16) _Float16 actH[2][NACT];      // 1792 B
    __shared__ float ctrlB[2][NCTRL];
    __shared__ float gA[2][512];
    __shared__ float iA[2][NCTRL];
    __shared__ float hA[2][NCTRL];
    __shared__ __align__(16) float readv[2][NWORD], keyv[2][NWORD], ev[2][NWORD], av[2][NWORD];
    __shared__ __align__(16) float cosb[2][NMEM], wb[2][NMEM], part[2][2 * NWORD];
    __shared__ float scal[2][2];
    __shared__ int len_sh[2], gpos[2];

    const int t = threadIdx.x;
    const int g = blockIdx.x;
    const int cc = t >> 1;         // column 0..511 (sweep mapping)
    const int hf = t & 1;          // k-range half

    if (t < 2) {
        int bb = 2 * g + t;
        int L = 0;
        for (int s = 0; s < NT; ++s) L += (batch_sizes[s] > bb);
        len_sh[t] = L;
    }
    if (t < NB) {   // inverse permutation: find out-position of each packed row
        int ug = unsort[t];
        if (ug == 2 * g)     gpos[0] = t;
        if (ug == 2 * g + 1) gpos[1] = t;
    }
    for (int i = t; i < 2 * NMEM * NWORD; i += 1024) {
        int ii = i & (NMEM * NWORD - 1);
        M[i >> 14][ii >> 7][ii & 127] = M0[ii];
    }
    if (t < 512) {
        const int q = t >> 8, u = t & 255;
        ctrlB[q][u] = 0.0f;
        actH[q][192 + u] = (_Float16)0.0f;
        if (u < NWORD) readv[q][u] = 0.0f;
    }
    __syncthreads();
    const int len0 = len_sh[0], len1 = len_sh[1];   // len0 >= len1 (packed order)

    // per-column biases (meaningful on hf==0 lanes; loads are in-bounds for all)
    const float bRZ  = wsB[B_BA + cc];
    const float bAux = (cc < 256) ? wsB[B_BNI + cc] : wsB[B_BNH + (cc - 256)];
    const float bHD  = wsB[B_BH + cc];

    const h8* __restrict__ pA  = (const h8*)(wsH + H_WA);
    const h8* __restrict__ pI  = (const h8*)(wsH + H_WNI);
    const h8* __restrict__ pH  = (const h8*)(wsH + H_WNH);
    const h8* __restrict__ pHD = (const h8*)(wsH + H_WH);
    const h8* A0 = (const h8*)actH[0];
    const h8* A1 = (const h8*)actH[1];

    for (int ts = 0; ts < len0; ++ts) {
        // ---- phase 1: stage activations as fp16 (t<512, round-2 mapping)
        if (t < 512) {
            const int q = t >> 8, u = t & 255;
            if (u < 128)      actH[q][64 + u] = (_Float16)readv[q][u];
            else if (u < 192) actH[q][u - 128] =
                (_Float16)data[((long)ts * NB + (2 * g + q)) * NDIN + (u - 128)];
        }
        __syncthreads();

        // ---- phase 2: rz sweep (col cc, k-half hf, both rows)
        {
            float a0 = hf ? 0.f : bRZ, c0 = 0.f, a1 = hf ? 0.f : bRZ, c1 = 0.f;
            #pragma unroll 4
            for (int kk = 0; kk < 28; ++kk) {
                int kc = hf * 28 + kk;
                LOADX(kc);
                DOT2R(pA[kc * 512 + cc]);
            }
            a0 += c0; a1 += c1;
            a0 += __shfl_xor(a0, 1);
            a1 += __shfl_xor(a1, 1);
            if (!hf) { gA[0][cc] = a0; gA[1][cc] = a1; }
        }
        // ---- aux sweep: inn (cc<256) or hn (cc>=256)
        {
            float a0 = hf ? 0.f : bAux, c0 = 0.f, a1 = hf ? 0.f : bAux, c1 = 0.f;
            const int ac = cc & 255;
            if (cc < 256) {
                #pragma unroll 4
                for (int kk = 0; kk < 12; ++kk) {
                    int kc = hf * 12 + kk;
                    LOADX(kc);
                    DOT2R(pI[kc * 256 + ac]);
                }
            } else {
                #pragma unroll 4
                for (int kk = 0; kk < 16; ++kk) {
                    int kcH = hf * 16 + kk;
                    LOADX(24 + kcH);
                    DOT2R(pH[kcH * 256 + ac]);
                }
            }
            a0 += c0; a1 += c1;
            a0 += __shfl_xor(a0, 1);
            a1 += __shfl_xor(a1, 1);
            if (!hf) {
                if (cc < 256) { iA[0][ac] = a0; iA[1][ac] = a1; }
                else          { hA[0][ac] = a0; hA[1][ac] = a1; }
            }
        }
        __syncthreads();

        // ---- phase 3: gate combine (t<512)
        if (t < 512) {
            const int q = t >> 8, u = t & 255;
            const bool wr = (q == 0) | (ts < len1);
            float rg = sigf(gA[q][u]);
            float zg = sigf(gA[q][NCTRL + u]);
            float ng = tanhf(fmaf(rg, hA[q][u], iA[q][u]));
            float cold = ctrlB[q][u];
            float cnew = fmaf(zg, cold - ng, ng);
            if (wr) {
                ctrlB[q][u] = cnew;
                actH[q][192 + u] = (_Float16)cnew;
            }
        }
        __syncthreads();

        // ---- phase 4: heads sweep (col cc, k-half hf, both rows)
        {
            float a0 = hf ? 0.f : bHD, c0 = 0.f, a1 = hf ? 0.f : bHD, c1 = 0.f;
            #pragma unroll 4
            for (int kk = 0; kk < 16; ++kk) {
                int kcH = hf * 16 + kk;
                LOADX(24 + kcH);
                DOT2R(pHD[kcH * 512 + cc]);
            }
            a0 += c0; a1 += c1;
            a0 += __shfl_xor(a0, 1);
            a1 += __shfl_xor(a1, 1);
            if (!hf) {
                if (cc < 128)       { keyv[0][cc] = tanhf(a0);      keyv[1][cc] = tanhf(a1); }
                else if (cc < 256)  { ev[0][cc - 128] = sigf(a0);   ev[1][cc - 128] = sigf(a1); }
                else if (cc < 384)  { av[0][cc - 256] = a0;         av[1][cc - 256] = a1; }
                else if (cc == 384) { scal[0][1] = softplusf(a0);   scal[1][1] = softplusf(a1); }
            }
        }
        __syncthreads();

        // ---- phase 5: ||k|| (t<512, u<64 per row)
        if (t < 512) {
            const int q = t >> 8, u = t & 255;
            if (u < 64) {
                float s = keyv[q][u] * keyv[q][u] + keyv[q][u + 64] * keyv[q][u + 64];
                #pragma unroll
                for (int o = 32; o >= 1; o >>= 1) s += __shfl_xor(s, o);
                if (u == 0) scal[q][0] = 1.0f / (sqrtf(s) + EPSF);
            }
        }
        __syncthreads();

        // ---- phase 6: cosine sim (t<512: 2 threads / mem-row per data-row)
        if (t < 512) {
            const int q = t >> 8, u = t & 255;
            int rr = u >> 1, hh = u & 1;
            const float* Mr = &M[q][rr][hh * 64];
            const float4* kk4 = (const float4*)(&keyv[q][hh * 64]);
            float s2 = 0.f, sc = 0.f;
            #pragma unroll
            for (int p = 0; p < 16; ++p) {
                float4 k4 = kk4[p];
                float m0 = Mr[4 * p], m1 = Mr[4 * p + 1], m2 = Mr[4 * p + 2], m3 = Mr[4 * p + 3];
                s2 = fmaf(m0, m0, s2); sc = fmaf(m0, k4.x, sc);
                s2 = fmaf(m1, m1, s2); sc = fmaf(m1, k4.y, sc);
                s2 = fmaf(m2, m2, s2); sc = fmaf(m2, k4.z, sc);
                s2 = fmaf(m3, m3, s2); sc = fmaf(m3, k4.w, sc);
            }
            s2 += __shfl_xor(s2, 1);
            sc += __shfl_xor(sc, 1);
            if (hh == 0) cosb[q][rr] = sc * scal[q][0] / (sqrtf(s2) + EPSF);
        }
        __syncthreads();

        // ---- phase 7: softmax over 128 logits (t<512, u<64 per row)
        if (t < 512) {
            const int q = t >> 8, u = t & 255;
            if (u < 64) {
                float beta = scal[q][1];
                float l0 = beta * cosb[q][u], l1 = beta * cosb[q][u + 64];
                float mx = fmaxf(l0, l1);
                #pragma unroll
                for (int o = 32; o >= 1; o >>= 1) mx = fmaxf(mx, __shfl_xor(mx, o));
                float se0 = expf(l0 - mx), se1 = expf(l1 - mx);
                float s = se0 + se1;
                #pragma unroll
                for (int o = 32; o >= 1; o >>= 1) s += __shfl_xor(s, o);
                float inv = 1.0f / s;
                wb[q][u] = se0 * inv;
                wb[q][u + 64] = se1 * inv;
            }
        }
        __syncthreads();

        // ---- phase 8: FUSED read+update (t<512)
        if (t < 512) {
            const int q = t >> 8, u = t & 255;
            const bool wr = (q == 0) | (ts < len1);
            int j = u & 127, rh = u >> 7;
            float ej = ev[q][j], aj = av[q][j];
            const float4* wb4 = (const float4*)(&wb[q][rh * 64]);
            float p = 0.f;
            #pragma unroll
            for (int pq = 0; pq < 16; ++pq) {
                float4 w4 = wb4[pq];
                int r = rh * 64 + 4 * pq;
                float m0 = M[q][r][j], m1 = M[q][r + 1][j], m2 = M[q][r + 2][j], m3 = M[q][r + 3][j];
                p = fmaf(w4.x, m0, p);
                p = fmaf(w4.y, m1, p);
                p = fmaf(w4.z, m2, p);
                p = fmaf(w4.w, m3, p);
                if (wr) {
                    M[q][r][j]     = fmaf(-w4.x, fmaf(ej, m0, -aj), m0);
                    M[q][r + 1][j] = fmaf(-w4.y, fmaf(ej, m1, -aj), m1);
                    M[q][r + 2][j] = fmaf(-w4.z, fmaf(ej, m2, -aj), m2);
                    M[q][r + 3][j] = fmaf(-w4.w, fmaf(ej, m3, -aj), m3);
                }
            }
            part[q][rh * 128 + j] = p;
        }
        __syncthreads();
        if (t < 512) {
            const int q = t >> 8, u = t & 255;
            const bool wr = (q == 0) | (ts < len1);
            if (wr && u < 128) readv[q][u] = part[q][u] + part[q][128 + u];
            // readv[u] produced and consumed by thread u -> no barrier here
        }
    }

    if (t < 512) {
        const int q = t >> 8, u = t & 255;
        out[gpos[q] * NCTRL + u] = ctrlB[q][u];
        if (u < NWORD) out[NB * NCTRL + gpos[q] * NWORD + u] = readv[q][u];
    }
}

// FALLBACK (ws too small): verified slow path.
__global__ __launch_bounds__(256) void ntm_slow(
    const float* __restrict__ data, const int* __restrict__ batch_sizes,
    const int* __restrict__ unsort,
    const float* __restrict__ Wih, const float* __restrict__ bih,
    const float* __restrict__ Whh, const float* __restrict__ bhh,
    const float* __restrict__ Wkey, const float* __restrict__ bkey,
    const float* __restrict__ Wbeta, const float* __restrict__ bbeta,
    const float* __restrict__ Wer, const float* __restrict__ ber,
    const float* __restrict__ Wadd, const float* __restrict__ badd,
    const float* __restrict__ M0, float* __restrict__ out)
{
    __shared__ float M[NMEM][NWORD + 1];
    __shared__ float act[NACT];
    __shared__ float ctrlB[NCTRL];
    __shared__ float gpre[512], ginn[256], ghn[256], hpre[448];
    __shared__ __align__(16) float readv[NWORD], keyv[NWORD], ev[NWORD], av[NWORD];
    __shared__ __align__(16) float cosb[NMEM], wb[NMEM], part[2 * NWORD], scal[2];
    __shared__ int len_sh;

    const int tid = threadIdx.x;
    const int g = blockIdx.x;
    const int b = unsort[g];

    if (tid == 0) {
        int L = 0;
        for (int t = 0; t < NT; ++t) L += (batch_sizes[t] > b);
        len_sh = L;
    }
    for (int i = tid; i < NMEM * NWORD; i += 256)
        M[i >> 7][i & 127] = M0[i];
    ctrlB[tid] = 0.0f;
    if (tid < NWORD) readv[tid] = 0.0f;
    __syncthreads();
    const int len = len_sh;
    const int wave = tid >> 6, lane = tid & 63;

    for (int t = 0; t < len; ++t) {
        if (tid < 64)  act[tid] = data[((long)t * NB + b) * NDIN + tid];
        if (tid < 128) act[64 + tid] = readv[tid];
        act[192 + tid] = ctrlB[tid];
        __syncthreads();

        for (int j = wave; j < 512; j += 4) {
            float p = 0.f;
            for (int k = lane; k < 192; k += 64) p = fmaf(act[k], Wih[j * 192 + k], p);
            for (int k = lane; k < 256; k += 64) p = fmaf(act[192 + k], Whh[j * 256 + k], p);
            #pragma unroll
            for (int o = 32; o >= 1; o >>= 1) p += __shfl_xor(p, o);
            if (lane == 0) gpre[j] = p;
        }
        for (int j = wave; j < 256; j += 4) {
            float pi = 0.f, ph = 0.f;
            for (int k = lane; k < 192; k += 64) pi = fmaf(act[k], Wih[(512 + j) * 192 + k], pi);
            for (int k = lane; k < 256; k += 64) ph = fmaf(act[192 + k], Whh[(512 + j) * 256 + k], ph);
            #pragma unroll
            for (int o = 32; o >= 1; o >>= 1) { pi += __shfl_xor(pi, o); ph += __shfl_xor(ph, o); }
            if (lane == 0) { ginn[j] = pi; ghn[j] = ph; }
        }
        __syncthreads();
        {
            float r = sigf(gpre[tid] + bih[tid] + bhh[tid]);
            float z = sigf(gpre[256 + tid] + bih[256 + tid] + bhh[256 + tid]);
            float inn = ginn[tid] + bih[512 + tid];
            float hn  = ghn[tid] + bhh[512 + tid];
            float n = tanhf(fmaf(r, hn, inn));
            float cold = act[192 + tid];
            ctrlB[tid] = fmaf(z, cold - n, n);
        }
        __syncthreads();
        for (int j = wave; j < 385; j += 4) {
            const float* Wp; long base;
            if (j < 128)      { Wp = Wkey;  base = (long)j * 256; }
            else if (j < 256) { Wp = Wer;   base = (long)(j - 128) * 256; }
            else if (j < 384) { Wp = Wadd;  base = (long)(j - 256) * 256; }
            else              { Wp = Wbeta; base = 0; }
            float p = 0.f;
            for (int k = lane; k < 256; k += 64) p = fmaf(ctrlB[k], Wp[base + k], p);
            #pragma unroll
            for (int o = 32; o >= 1; o >>= 1) p += __shfl_xor(p, o);
            if (lane == 0) hpre[j] = p;
        }
        __syncthreads();
        if (tid < 128) {
            keyv[tid] = tanhf(hpre[tid] + bkey[tid]);
            ev[tid]   = sigf(hpre[128 + tid] + ber[tid]);
            av[tid]   = hpre[256 + tid] + badd[tid];
        }
        if (tid == 0) scal[1] = softplusf(hpre[384] + bbeta[0]);
        __syncthreads();

        memory_step(tid, true, M, keyv, ev, av, cosb, wb, part, readv, scal);
        __syncthreads();
    }

    out[g * NCTRL + tid] = ctrlB[tid];
    if (tid < NWORD) out[NB * NCTRL + g * NWORD + tid] = readv[tid];
}

extern "C" void kernel_launch(void* const* d_in, const int* in_sizes, int n_in,
                              void* d_out, int out_size, void* d_ws, size_t ws_size,
                              hipStream_t stream)
{
    const float* data       = (const float*)d_in[0];
    const int*  batch_sizes = (const int*)d_in[1];
    const int*  unsort      = (const int*)d_in[2];
    float* out = (float*)d_out;

    if (ws_size >= (size_t)WS_BYTES) {
        _Float16* wsH = (_Float16*)d_ws;
        float* wsB = (float*)((char*)d_ws + (size_t)H_TOTAL * 2);
        prep_kernel<<<(H_TOTAL + B_TOTAL + 255) / 256, 256, 0, stream>>>(
            (const float*)d_in[3], (const float*)d_in[4], (const float*)d_in[5],
            (const float*)d_in[6], (const float*)d_in[7], (const float*)d_in[8],
            (const float*)d_in[9], (const float*)d_in[10], (const float*)d_in[11],
            (const float*)d_in[12], (const float*)d_in[13], (const float*)d_in[14],
            wsH, wsB);
        ntm_fast5<<<NB / 2, 1024, 0, stream>>>(data, batch_sizes, unsort,
                                               (const float*)d_in[15], wsH, wsB, out);
    } else {
        ntm_slow<<<NB, 256, 0, stream>>>(
            data, batch_sizes, unsort,
            (const float*)d_in[3], (const float*)d_in[4], (const float*)d_in[5],
            (const float*)d_in[6], (const float*)d_in[7], (const float*)d_in[8],
            (const float*)d_in[9], (const float*)d_in[10], (const float*)d_in[11],
            (const float*)d_in[12], (const float*)d_in[13], (const float*)d_in[14],
            (const float*)d_in[15], out);
    }
}

// Round 8
// 7573.730 us; speedup vs baseline: 2.8418x; 2.1869x over previous
//
#include <hip/hip_runtime.h>
#include <math.h>

#define NB 512      // batch
#define NT 512      // time
#define NCTRL 256
#define NWORD 128
#define NMEM 128
#define NDIN 64
#define NACT 448    // x(64) | read(128) | ctrl(256)
#define EPSF 1e-6f

// fp16 weight panel, CHUNK-TRANSPOSED layout (identical to prior rounds):
//   element(region, kc, col, e) at region_base + (kc*NCOLS + col)*8 + e
#define H_WA   0        // rz:    56 kc x 512 cols x 8
#define H_WNI  229376   // inn:   24 kc x 256 cols x 8
#define H_WNH  278528   // hn:    32 kc x 256 cols x 8
#define H_WH   344064   // heads: 32 kc x 512 cols x 8 (key|erase|add|beta|pad)
#define H_TOTAL 475136
#define B_BA   0        // [512] b_ih+b_hh (r,z)
#define B_BNI  512      // [256]
#define B_BNH  768      // [256]
#define B_BH   1024     // [512]
#define B_TOTAL 1536
#define WS_BYTES (H_TOTAL * 2 + B_TOTAL * 4)

typedef _Float16 h2 __attribute__((ext_vector_type(2)));
typedef _Float16 h8 __attribute__((ext_vector_type(8)));
union H8 { h8 v; h2 d[4]; };

__device__ __forceinline__ float sigf(float x) { return 1.0f / (1.0f + expf(-x)); }
__device__ __forceinline__ float softplusf(float x) {
    return (x > 15.0f) ? x : log1pf(expf(x));
}
__device__ __forceinline__ float fdot2(h2 a, h2 b, float c) {
#if __has_builtin(__builtin_amdgcn_fdot2)
    return __builtin_amdgcn_fdot2(a, b, c, false);
#else
    return fmaf((float)a[0], (float)b[0], fmaf((float)a[1], (float)b[1], c));
#endif
}

// lgkm-only barrier: orders LDS traffic without draining vmcnt (in-loop
// inter-thread communication is all via LDS; the compiler still inserts
// per-value vmcnt waits for each thread's own global loads).
__device__ __forceinline__ void barL() {
    asm volatile("s_waitcnt lgkmcnt(0)\n\ts_barrier" ::: "memory");
}

__global__ __launch_bounds__(256) void prep_kernel(
    const float* __restrict__ Wih, const float* __restrict__ bih,
    const float* __restrict__ Whh, const float* __restrict__ bhh,
    const float* __restrict__ Wkey, const float* __restrict__ bkey,
    const float* __restrict__ Wbeta, const float* __restrict__ bbeta,
    const float* __restrict__ Wer, const float* __restrict__ ber,
    const float* __restrict__ Wadd, const float* __restrict__ badd,
    _Float16* __restrict__ wsH, float* __restrict__ wsB)
{
    int i = blockIdx.x * 256 + threadIdx.x;
    if (i < H_TOTAL) {
        float v;
        if (i < H_WNI) {                       // rz [kc][512][8]
            int ch = i >> 3, e = i & 7;
            int kc = ch >> 9, col = ch & 511;
            int k = kc * 8 + e;
            v = (k < 192) ? Wih[col * 192 + k] : Whh[col * 256 + (k - 192)];
        } else if (i < H_WNH) {                // inn [kc][256][8], k<192
            int i2 = i - H_WNI; int ch = i2 >> 3, e = i2 & 7;
            int kc = ch >> 8, col = ch & 255;
            v = Wih[(512 + col) * 192 + kc * 8 + e];
        } else if (i < H_WH) {                 // hn [kc][256][8], k<256
            int i2 = i - H_WNH; int ch = i2 >> 3, e = i2 & 7;
            int kc = ch >> 8, col = ch & 255;
            v = Whh[(512 + col) * 256 + kc * 8 + e];
        } else {                               // heads [kc][512][8], k<256
            int i2 = i - H_WH; int ch = i2 >> 3, e = i2 & 7;
            int kc = ch >> 9, col = ch & 511;
            int k = kc * 8 + e;
            if (col < 128)       v = Wkey[col * 256 + k];
            else if (col < 256)  v = Wer[(col - 128) * 256 + k];
            else if (col < 384)  v = Wadd[(col - 256) * 256 + k];
            else if (col == 384) v = Wbeta[k];
            else                 v = 0.0f;
        }
        wsH[i] = (_Float16)v;
    } else if (i < H_TOTAL + B_TOTAL) {
        int j = i - H_TOTAL;
        float v;
        if (j < 512)        v = bih[j] + bhh[j];
        else if (j < 768)   v = bih[512 + (j - 512)];
        else if (j < 1024)  v = bhh[512 + (j - 768)];
        else {
            int c = j - 1024;
            if (c < 128)       v = bkey[c];
            else if (c < 256)  v = ber[c - 128];
            else if (c < 384)  v = badd[c - 256];
            else if (c == 384) v = bbeta[0];
            else               v = 0.0f;
        }
        wsB[j] = v;
    }
}

// Verified memory module (used by slow path only).
__device__ __forceinline__ void memory_step(
    int u, bool wr, float (*M)[NWORD + 1],
    const float* keyv, const float* ev, const float* av,
    float* cosb, float* wb, float* part, float* readv, float* scal)
{
    if (u < 64) {                       // ||k||
        float s = keyv[u] * keyv[u] + keyv[u + 64] * keyv[u + 64];
        #pragma unroll
        for (int o = 32; o >= 1; o >>= 1) s += __shfl_xor(s, o);
        if (u == 0) scal[0] = 1.0f / (sqrtf(s) + EPSF);
    }
    __syncthreads();
    {                                      // cosine sim: 2 threads / row
        int rr = u >> 1, hh = u & 1;
        const float* Mr = &M[rr][hh * 64];
        const float4* kk4 = (const float4*)(keyv + hh * 64);
        float s2 = 0.f, sc = 0.f;
        #pragma unroll
        for (int p = 0; p < 16; ++p) {
            float4 k4 = kk4[p];
            float m0 = Mr[4 * p], m1 = Mr[4 * p + 1], m2 = Mr[4 * p + 2], m3 = Mr[4 * p + 3];
            s2 = fmaf(m0, m0, s2); sc = fmaf(m0, k4.x, sc);
            s2 = fmaf(m1, m1, s2); sc = fmaf(m1, k4.y, sc);
            s2 = fmaf(m2, m2, s2); sc = fmaf(m2, k4.z, sc);
            s2 = fmaf(m3, m3, s2); sc = fmaf(m3, k4.w, sc);
        }
        s2 += __shfl_xor(s2, 1);
        sc += __shfl_xor(sc, 1);
        if (hh == 0) cosb[rr] = sc * scal[0] / (sqrtf(s2) + EPSF);
    }
    __syncthreads();
    if (u < 64) {                       // softmax over 128 logits
        float beta = scal[1];
        float l0 = beta * cosb[u], l1 = beta * cosb[u + 64];
        float mx = fmaxf(l0, l1);
        #pragma unroll
        for (int o = 32; o >= 1; o >>= 1) mx = fmaxf(mx, __shfl_xor(mx, o));
        float e0 = expf(l0 - mx), e1 = expf(l1 - mx);
        float s = e0 + e1;
        #pragma unroll
        for (int o = 32; o >= 1; o >>= 1) s += __shfl_xor(s, o);
        float inv = 1.0f / s;
        wb[u] = e0 * inv;
        wb[u + 64] = e1 * inv;
    }
    __syncthreads();
    {   // FUSED read+update
        int j = u & 127, rh = u >> 7;
        float ej = ev[j], aj = av[j];
        const float4* wb4 = (const float4*)(wb + rh * 64);
        float p = 0.f;
        #pragma unroll
        for (int pq = 0; pq < 16; ++pq) {
            float4 w4 = wb4[pq];
            int r = rh * 64 + 4 * pq;
            float m0 = M[r][j], m1 = M[r + 1][j], m2 = M[r + 2][j], m3 = M[r + 3][j];
            p = fmaf(w4.x, m0, p);
            p = fmaf(w4.y, m1, p);
            p = fmaf(w4.z, m2, p);
            p = fmaf(w4.w, m3, p);
            if (wr) {
                M[r][j]     = fmaf(-w4.x, fmaf(ej, m0, -aj), m0);
                M[r + 1][j] = fmaf(-w4.y, fmaf(ej, m1, -aj), m1);
                M[r + 2][j] = fmaf(-w4.z, fmaf(ej, m2, -aj), m2);
                M[r + 3][j] = fmaf(-w4.w, fmaf(ej, m3, -aj), m3);
            }
        }
        part[rh * 128 + j] = p;
    }
    __syncthreads();
    if (wr && u < 128) readv[u] = part[u] + part[128 + u];
}

#define DOT_RZ(WSRC) do { H8 w_; w_.v = (WSRC); \
    a0 = fdot2(x0.d[0], w_.d[0], a0); c0 = fdot2(x0.d[1], w_.d[1], c0); \
    a0 = fdot2(x0.d[2], w_.d[2], a0); c0 = fdot2(x0.d[3], w_.d[3], c0); \
    a1 = fdot2(x1.d[0], w_.d[0], a1); c1 = fdot2(x1.d[1], w_.d[1], c1); \
    a1 = fdot2(x1.d[2], w_.d[2], a1); c1 = fdot2(x1.d[3], w_.d[3], c1); } while (0)

#define DOT_AUX(WSRC) do { H8 w_; w_.v = (WSRC); \
    e0 = fdot2(x0.d[0], w_.d[0], e0); f0 = fdot2(x0.d[1], w_.d[1], f0); \
    e0 = fdot2(x0.d[2], w_.d[2], e0); f0 = fdot2(x0.d[3], w_.d[3], f0); \
    e1 = fdot2(x1.d[0], w_.d[0], e1); f1 = fdot2(x1.d[1], w_.d[1], f1); \
    e1 = fdot2(x1.d[2], w_.d[2], e1); f1 = fdot2(x1.d[3], w_.d[3], f1); } while (0)

#define DOT_HD(WSRC) do { H8 w_; w_.v = (WSRC); \
    h0 = fdot2(x0.d[0], w_.d[0], h0); d0 = fdot2(x0.d[1], w_.d[1], d0); \
    h0 = fdot2(x0.d[2], w_.d[2], h0); d0 = fdot2(x0.d[3], w_.d[3], d0); \
    h1 = fdot2(x1.d[0], w_.d[0], h1); d1 = fdot2(x1.d[1], w_.d[1], d1); \
    h1 = fdot2(x1.d[2], w_.d[2], h1); d1 = fdot2(x1.d[3], w_.d[3], d1); } while (0)

#define LOADX(KC) H8 x0; x0.v = A0[KC]; H8 x1; x1.v = A1[KC]

// Software-pipelined 2-row kernel (round-2 base, 96-VGPR-class pressure).
// Memory module of step ts-1 is interleaved with the read-INDEPENDENT sweep
// chunks of step ts (x/ctrl regions: rz kc0..7,24..55 + hn + inn kc0..7 =
// 754 KB of 950 KB), so the L2 port stays busy during the formerly-idle
// LDS-bound memory phases. Only the read-dependent slice (rz+inn kc8..23,
// 196 KB) + gates + heads remain serial. Accumulators (8 floats) carry
// across barL barriers in registers; NO weight values are held across
// phases -> no spill risk under the compiler's 128-reg cap.
__global__ __launch_bounds__(512) void ntm_fast6(
    const float* __restrict__ data, const int* __restrict__ batch_sizes,
    const int* __restrict__ unsort, const float* __restrict__ M0,
    const _Float16* __restrict__ wsH, const float* __restrict__ wsB,
    float* __restrict__ out)
{
    __shared__ float M[2][NMEM][NWORD + 1];               // 132096 B
    __shared__ __align__(16) _Float16 actH[2][NACT];      // 1792 B
    __shared__ float ctrlB[2][NCTRL];
    __shared__ float gA[2][512];
    __shared__ float iA[2][NCTRL];
    __shared__ float hA[2][NCTRL];
    __shared__ __align__(16) float readv[2][NWORD], keyv[2][NWORD], ev[2][NWORD], av[2][NWORD];
    __shared__ __align__(16) float cosb[2][NMEM], wb[2][NMEM], part[2][2 * NWORD];
    __shared__ float kn2[2][2], betav[2];
    __shared__ int len_sh[2], gpos[2];

    const int t = threadIdx.x;
    const int q = t >> 8;          // row half (0/1)
    const int u = t & 255;         // local tid within half
    const int g = blockIdx.x;
    const int b = 2 * g + q;       // this half's packed row

    if (t < 2) {
        int bb = 2 * g + t;
        int L = 0;
        for (int s = 0; s < NT; ++s) L += (batch_sizes[s] > bb);
        len_sh[t] = L;
    }
    {   // inverse permutation: find out-position of each packed row
        int ug = unsort[t];                 // t in [0,512) == NB
        if (ug == 2 * g)     gpos[0] = t;
        if (ug == 2 * g + 1) gpos[1] = t;
    }
    for (int i = t; i < 2 * NMEM * NWORD; i += 512) {
        int ii = i & (NMEM * NWORD - 1);
        M[i >> 14][ii >> 7][ii & 127] = M0[ii];
    }
    ctrlB[q][u] = 0.0f;
    actH[q][192 + u] = (_Float16)0.0f;
    if (u < NWORD) { readv[q][u] = 0.0f; actH[q][64 + u] = (_Float16)0.0f; }
    __syncthreads();
    const int len0 = len_sh[0], len1 = len_sh[1];   // len0 >= len1 (packed order)

    const float bRZ  = wsB[B_BA + t];
    const float bAux = (t < 256) ? wsB[B_BNI + u] : wsB[B_BNH + u];
    const float bHD  = wsB[B_BH + t];

    const h8* __restrict__ pA  = (const h8*)(wsH + H_WA);
    const h8* __restrict__ pI  = (const h8*)(wsH + H_WNI);
    const h8* __restrict__ pH  = (const h8*)(wsH + H_WNH);
    const h8* __restrict__ pHD = (const h8*)(wsH + H_WH);
    const h8* A0 = (const h8*)actH[0];
    const h8* A1 = (const h8*)actH[1];

    // ================= PROLOGUE: step 0 (no pipeline) =================
    float xf = 0.0f;
    if (u >= 128 && u < 192) {
        xf = data[((long)0 * NB + b) * NDIN + (u - 128)];
        actH[q][u - 128] = (_Float16)xf;
    }
    barL();
    {   // full rz+aux sweep for ts=0
        float a0 = bRZ, c0 = 0.f, a1 = bRZ, c1 = 0.f;
        float e0 = bAux, f0 = 0.f, e1 = bAux, f1 = 0.f;
        if (t < 256) {
            #pragma unroll 4
            for (int kc = 0; kc < 24; ++kc) { LOADX(kc); DOT_RZ(pA[kc * 512 + t]); DOT_AUX(pI[kc * 256 + u]); }
            #pragma unroll 4
            for (int kc = 24; kc < 56; ++kc) { LOADX(kc); DOT_RZ(pA[kc * 512 + t]); }
        } else {
            #pragma unroll 4
            for (int kc = 0; kc < 24; ++kc) { LOADX(kc); DOT_RZ(pA[kc * 512 + t]); }
            #pragma unroll 4
            for (int kc = 24; kc < 56; ++kc) { LOADX(kc); DOT_RZ(pA[kc * 512 + t]); DOT_AUX(pH[(kc - 24) * 256 + u]); }
        }
        gA[0][t] = a0 + c0; gA[1][t] = a1 + c1;
        if (t < 256) { iA[0][u] = e0 + f0; iA[1][u] = e1 + f1; }
        else         { hA[0][u] = e0 + f0; hA[1][u] = e1 + f1; }
    }
    barL();
    {   // gates(0) — ts=0 is active for both rows (len >= 1)
        float rg = sigf(gA[q][u]);
        float zg = sigf(gA[q][NCTRL + u]);
        float ng = tanhf(fmaf(rg, hA[q][u], iA[q][u]));
        float cold = ctrlB[q][u];
        float cnew = fmaf(zg, cold - ng, ng);
        ctrlB[q][u] = cnew;
        actH[q][192 + u] = (_Float16)cnew;
    }
    barL();
    {   // heads(0) + kn2 butterfly + prefetch x(1)
        float h0 = bHD, d0 = 0.f, h1 = bHD, d1 = 0.f;
        #pragma unroll 4
        for (int i = 0; i < 32; ++i) { LOADX(24 + i); DOT_HD(pHD[i * 512 + t]); }
        h0 += d0; h1 += d1;
        if (t < 128) {
            float k0 = tanhf(h0), k1 = tanhf(h1);
            keyv[0][t] = k0; keyv[1][t] = k1;
            float s0 = k0 * k0, s1 = k1 * k1;
            #pragma unroll
            for (int o = 32; o >= 1; o >>= 1) { s0 += __shfl_xor(s0, o); s1 += __shfl_xor(s1, o); }
            if ((t & 63) == 0) { kn2[0][t >> 6] = s0; kn2[1][t >> 6] = s1; }
        }
        else if (t < 256)  { ev[0][t - 128] = sigf(h0); ev[1][t - 128] = sigf(h1); }
        else if (t < 384)  { av[0][t - 256] = h0;       av[1][t - 256] = h1; }
        else if (t == 384) { betav[0] = softplusf(h0);  betav[1] = softplusf(h1); }
        int tn = (1 < NT) ? 1 : (NT - 1);
        if (u >= 128 && u < 192) xf = data[((long)tn * NB + b) * NDIN + (u - 128)];
    }
    barL();

    // ================= PIPELINED LOOP =================
    // iteration ts: memory(p=ts-1) interleaved with indep sweep(ts);
    // then dep sweep(ts), gates(ts), heads(ts). Last iter (ts==len0) runs
    // only the memory epilogue (runs==false skips sweep/gates/heads).
    for (int ts = 1; ts <= len0; ++ts) {
        const int p = ts - 1;
        const bool wrp = (q == 0) | (p < len1);
        const bool wrt = (q == 0) | (ts < len1);
        const bool runs = (ts < len0);
        float a0 = bRZ, c0 = 0.f, a1 = bRZ, c1 = 0.f;
        float e0 = bAux, f0 = 0.f, e1 = bAux, f1 = 0.f;

        // ---- SEG A: stage x(ts) | rz kc24..34 + hn 0..9 | cos(p)
        if (runs) {
            if (u >= 128 && u < 192) actH[q][u - 128] = (_Float16)xf;
            #pragma unroll 4
            for (int kc = 24; kc < 35; ++kc) { LOADX(kc); DOT_RZ(pA[kc * 512 + t]); }
            if (t >= 256) {
                #pragma unroll 4
                for (int i = 0; i < 10; ++i) { LOADX(24 + i); DOT_AUX(pH[i * 256 + u]); }
            }
        }
        {   // cosine sim (p): 2 threads / mem-row
            float invk = 1.0f / (sqrtf(kn2[q][0] + kn2[q][1]) + EPSF);
            int rr = u >> 1, hh = u & 1;
            const float* Mr = &M[q][rr][hh * 64];
            const float4* kk4 = (const float4*)(&keyv[q][hh * 64]);
            float s2 = 0.f, sc = 0.f;
            #pragma unroll
            for (int pp = 0; pp < 16; ++pp) {
                float4 k4 = kk4[pp];
                float m0 = Mr[4 * pp], m1 = Mr[4 * pp + 1], m2 = Mr[4 * pp + 2], m3 = Mr[4 * pp + 3];
                s2 = fmaf(m0, m0, s2); sc = fmaf(m0, k4.x, sc);
                s2 = fmaf(m1, m1, s2); sc = fmaf(m1, k4.y, sc);
                s2 = fmaf(m2, m2, s2); sc = fmaf(m2, k4.z, sc);
                s2 = fmaf(m3, m3, s2); sc = fmaf(m3, k4.w, sc);
            }
            s2 += __shfl_xor(s2, 1);
            sc += __shfl_xor(sc, 1);
            if (hh == 0) cosb[q][rr] = sc * invk / (sqrtf(s2) + EPSF);
        }
        barL();

        // ---- SEG B: rz kc35..45 + hn 10..19 | softmax(p)
        if (runs) {
            #pragma unroll 4
            for (int kc = 35; kc < 46; ++kc) { LOADX(kc); DOT_RZ(pA[kc * 512 + t]); }
            if (t >= 256) {
                #pragma unroll 4
                for (int i = 10; i < 20; ++i) { LOADX(24 + i); DOT_AUX(pH[i * 256 + u]); }
            }
        }
        if (u < 64) {
            float beta = betav[q];
            float l0 = beta * cosb[q][u], l1 = beta * cosb[q][u + 64];
            float mx = fmaxf(l0, l1);
            #pragma unroll
            for (int o = 32; o >= 1; o >>= 1) mx = fmaxf(mx, __shfl_xor(mx, o));
            float se0 = expf(l0 - mx), se1 = expf(l1 - mx);
            float s = se0 + se1;
            #pragma unroll
            for (int o = 32; o >= 1; o >>= 1) s += __shfl_xor(s, o);
            float inv = 1.0f / s;
            wb[q][u] = se0 * inv;
            wb[q][u + 64] = se1 * inv;
        }
        barL();

        // ---- SEG C: rz kc46..55 + hn 20..31 | fused M read+update(p)
        if (runs) {
            #pragma unroll 4
            for (int kc = 46; kc < 56; ++kc) { LOADX(kc); DOT_RZ(pA[kc * 512 + t]); }
            if (t >= 256) {
                #pragma unroll 4
                for (int i = 20; i < 32; ++i) { LOADX(24 + i); DOT_AUX(pH[i * 256 + u]); }
            }
        }
        {
            int j = u & 127, rh = u >> 7;
            float ej = ev[q][j], aj = av[q][j];
            const float4* wb4 = (const float4*)(&wb[q][rh * 64]);
            float ps = 0.f;
            #pragma unroll
            for (int pq = 0; pq < 16; ++pq) {
                float4 w4 = wb4[pq];
                int r = rh * 64 + 4 * pq;
                float m0 = M[q][r][j], m1 = M[q][r + 1][j], m2 = M[q][r + 2][j], m3 = M[q][r + 3][j];
                ps = fmaf(w4.x, m0, ps);
                ps = fmaf(w4.y, m1, ps);
                ps = fmaf(w4.z, m2, ps);
                ps = fmaf(w4.w, m3, ps);
                if (wrp) {
                    M[q][r][j]     = fmaf(-w4.x, fmaf(ej, m0, -aj), m0);
                    M[q][r + 1][j] = fmaf(-w4.y, fmaf(ej, m1, -aj), m1);
                    M[q][r + 2][j] = fmaf(-w4.z, fmaf(ej, m2, -aj), m2);
                    M[q][r + 3][j] = fmaf(-w4.w, fmaf(ej, m3, -aj), m3);
                }
            }
            part[q][rh * 128 + j] = ps;
        }
        barL();

        // ---- SEG D: readv(p) combine + stage | rz kc0..7 + inn kc0..7
        if (runs) {
            if (t < 256) {
                #pragma unroll 4
                for (int kc = 0; kc < 8; ++kc) { LOADX(kc); DOT_RZ(pA[kc * 512 + t]); DOT_AUX(pI[kc * 256 + u]); }
            } else {
                #pragma unroll 4
                for (int kc = 0; kc < 8; ++kc) { LOADX(kc); DOT_RZ(pA[kc * 512 + t]); }
            }
        }
        if (wrp && u < 128) {
            float rv = part[q][u] + part[q][128 + u];
            readv[q][u] = rv;
            actH[q][64 + u] = (_Float16)rv;   // same-thread staging
        }
        barL();

        if (runs) {
            // ---- SEG E (dep): rz kc8..23 + inn kc8..23 -> finalize preacts
            if (t < 256) {
                #pragma unroll 4
                for (int kc = 8; kc < 24; ++kc) { LOADX(kc); DOT_RZ(pA[kc * 512 + t]); DOT_AUX(pI[kc * 256 + u]); }
            } else {
                #pragma unroll 4
                for (int kc = 8; kc < 24; ++kc) { LOADX(kc); DOT_RZ(pA[kc * 512 + t]); }
            }
            gA[0][t] = a0 + c0; gA[1][t] = a1 + c1;
            if (t < 256) { iA[0][u] = e0 + f0; iA[1][u] = e1 + f1; }
            else         { hA[0][u] = e0 + f0; hA[1][u] = e1 + f1; }
        }
        barL();

        if (runs) {
            {   // gates(ts)
                float rg = sigf(gA[q][u]);
                float zg = sigf(gA[q][NCTRL + u]);
                float ng = tanhf(fmaf(rg, hA[q][u], iA[q][u]));
                float cold = ctrlB[q][u];
                float cnew = fmaf(zg, cold - ng, ng);
                if (wrt) {
                    ctrlB[q][u] = cnew;
                    actH[q][192 + u] = (_Float16)cnew;
                }
            }
            barL();
            {   // heads(ts) + kn2 butterfly + prefetch x(ts+1)
                float h0 = bHD, d0 = 0.f, h1 = bHD, d1 = 0.f;
                #pragma unroll 4
                for (int i = 0; i < 32; ++i) { LOADX(24 + i); DOT_HD(pHD[i * 512 + t]); }
                h0 += d0; h1 += d1;
                if (t < 128) {
                    float k0 = tanhf(h0), k1 = tanhf(h1);
                    keyv[0][t] = k0; keyv[1][t] = k1;
                    float s0 = k0 * k0, s1 = k1 * k1;
                    #pragma unroll
                    for (int o = 32; o >= 1; o >>= 1) { s0 += __shfl_xor(s0, o); s1 += __shfl_xor(s1, o); }
                    if ((t & 63) == 0) { kn2[0][t >> 6] = s0; kn2[1][t >> 6] = s1; }
                }
                else if (t < 256)  { ev[0][t - 128] = sigf(h0); ev[1][t - 128] = sigf(h1); }
                else if (t < 384)  { av[0][t - 256] = h0;       av[1][t - 256] = h1; }
                else if (t == 384) { betav[0] = softplusf(h0);  betav[1] = softplusf(h1); }
                int tn = (ts + 1 < NT) ? (ts + 1) : (NT - 1);
                if (u >= 128 && u < 192) xf = data[((long)tn * NB + b) * NDIN + (u - 128)];
            }
            barL();
        }
    }

    out[gpos[q] * NCTRL + u] = ctrlB[q][u];
    if (u < NWORD) out[NB * NCTRL + gpos[q] * NWORD + u] = readv[q][u];
}

// FALLBACK (ws too small): verified slow path.
__global__ __launch_bounds__(256) void ntm_slow(
    const float* __restrict__ data, const int* __restrict__ batch_sizes,
    const int* __restrict__ unsort,
    const float* __restrict__ Wih, const float* __restrict__ bih,
    const float* __restrict__ Whh, const float* __restrict__ bhh,
    const float* __restrict__ Wkey, const float* __restrict__ bkey,
    const float* __restrict__ Wbeta, const float* __restrict__ bbeta,
    const float* __restrict__ Wer, const float* __restrict__ ber,
    const float* __restrict__ Wadd, const float* __restrict__ badd,
    const float* __restrict__ M0, float* __restrict__ out)
{
    __shared__ float M[NMEM][NWORD + 1];
    __shared__ float act[NACT];
    __shared__ float ctrlB[NCTRL];
    __shared__ float gpre[512], ginn[256], ghn[256], hpre[448];
    __shared__ __align__(16) float readv[NWORD], keyv[NWORD], ev[NWORD], av[NWORD];
    __shared__ __align__(16) float cosb[NMEM], wb[NMEM], part[2 * NWORD], scal[2];
    __shared__ int len_sh;

    const int tid = threadIdx.x;
    const int g = blockIdx.x;
    const int b = unsort[g];

    if (tid == 0) {
        int L = 0;
        for (int t = 0; t < NT; ++t) L += (batch_sizes[t] > b);
        len_sh = L;
    }
    for (int i = tid; i < NMEM * NWORD; i += 256)
        M[i >> 7][i & 127] = M0[i];
    ctrlB[tid] = 0.0f;
    if (tid < NWORD) readv[tid] = 0.0f;
    __syncthreads();
    const int len = len_sh;
    const int wave = tid >> 6, lane = tid & 63;

    for (int t = 0; t < len; ++t) {
        if (tid < 64)  act[tid] = data[((long)t * NB + b) * NDIN + tid];
        if (tid < 128) act[64 + tid] = readv[tid];
        act[192 + tid] = ctrlB[tid];
        __syncthreads();

        for (int j = wave; j < 512; j += 4) {
            float p = 0.f;
            for (int k = lane; k < 192; k += 64) p = fmaf(act[k], Wih[j * 192 + k], p);
            for (int k = lane; k < 256; k += 64) p = fmaf(act[192 + k], Whh[j * 256 + k], p);
            #pragma unroll
            for (int o = 32; o >= 1; o >>= 1) p += __shfl_xor(p, o);
            if (lane == 0) gpre[j] = p;
        }
        for (int j = wave; j < 256; j += 4) {
            float pi = 0.f, ph = 0.f;
            for (int k = lane; k < 192; k += 64) pi = fmaf(act[k], Wih[(512 + j) * 192 + k], pi);
            for (int k = lane; k < 256; k += 64) ph = fmaf(act[192 + k], Whh[(512 + j) * 256 + k], ph);
            #pragma unroll
            for (int o = 32; o >= 1; o >>= 1) { pi += __shfl_xor(pi, o); ph += __shfl_xor(ph, o); }
            if (lane == 0) { ginn[j] = pi; ghn[j] = ph; }
        }
        __syncthreads();
        {
            float r = sigf(gpre[tid] + bih[tid] + bhh[tid]);
            float z = sigf(gpre[256 + tid] + bih[256 + tid] + bhh[256 + tid]);
            float inn = ginn[tid] + bih[512 + tid];
            float hn  = ghn[tid] + bhh[512 + tid];
            float n = tanhf(fmaf(r, hn, inn));
            float cold = act[192 + tid];
            ctrlB[tid] = fmaf(z, cold - n, n);
        }
        __syncthreads();
        for (int j = wave; j < 385; j += 4) {
            const float* Wp; long base;
            if (j < 128)      { Wp = Wkey;  base = (long)j * 256; }
            else if (j < 256) { Wp = Wer;   base = (long)(j - 128) * 256; }
            else if (j < 384) { Wp = Wadd;  base = (long)(j - 256) * 256; }
            else              { Wp = Wbeta; base = 0; }
            float p = 0.f;
            for (int k = lane; k < 256; k += 64) p = fmaf(ctrlB[k], Wp[base + k], p);
            #pragma unroll
            for (int o = 32; o >= 1; o >>= 1) p += __shfl_xor(p, o);
            if (lane == 0) hpre[j] = p;
        }
        __syncthreads();
        if (tid < 128) {
            keyv[tid] = tanhf(hpre[tid] + bkey[tid]);
            ev[tid]   = sigf(hpre[128 + tid] + ber[tid]);
            av[tid]   = hpre[256 + tid] + badd[tid];
        }
        if (tid == 0) scal[1] = softplusf(hpre[384] + bbeta[0]);
        __syncthreads();

        memory_step(tid, true, M, keyv, ev, av, cosb, wb, part, readv, scal);
        __syncthreads();
    }

    out[g * NCTRL + tid] = ctrlB[tid];
    if (tid < NWORD) out[NB * NCTRL + g * NWORD + tid] = readv[tid];
}

extern "C" void kernel_launch(void* const* d_in, const int* in_sizes, int n_in,
                              void* d_out, int out_size, void* d_ws, size_t ws_size,
                              hipStream_t stream)
{
    const float* data       = (const float*)d_in[0];
    const int*  batch_sizes = (const int*)d_in[1];
    const int*  unsort      = (const int*)d_in[2];
    float* out = (float*)d_out;

    if (ws_size >= (size_t)WS_BYTES) {
        _Float16* wsH = (_Float16*)d_ws;
        float* wsB = (float*)((char*)d_ws + (size_t)H_TOTAL * 2);
        prep_kernel<<<(H_TOTAL + B_TOTAL + 255) / 256, 256, 0, stream>>>(
            (const float*)d_in[3], (const float*)d_in[4], (const float*)d_in[5],
            (const float*)d_in[6], (const float*)d_in[7], (const float*)d_in[8],
            (const float*)d_in[9], (const float*)d_in[10], (const float*)d_in[11],
            (const float*)d_in[12], (const float*)d_in[13], (const float*)d_in[14],
            wsH, wsB);
        ntm_fast6<<<NB / 2, 512, 0, stream>>>(data, batch_sizes, unsort,
                                              (const float*)d_in[15], wsH, wsB, out);
    } else {
        ntm_slow<<<NB, 256, 0, stream>>>(
            data, batch_sizes, unsort,
            (const float*)d_in[3], (const float*)d_in[4], (const float*)d_in[5],
            (const float*)d_in[6], (const float*)d_in[7], (const float*)d_in[8],
            (const float*)d_in[9], (const float*)d_in[10], (const float*)d_in[11],
            (const float*)d_in[12], (const float*)d_in[13], (const float*)d_in[14],
            (const float*)d_in[15], out);
    }
}

// Round 9
// 6521.297 us; speedup vs baseline: 3.3004x; 1.1614x over previous
//
#include <hip/hip_runtime.h>
#include <math.h>

#define NB 512      // batch
#define NT 512      // time
#define NCTRL 256
#define NWORD 128
#define NMEM 128
#define NDIN 64
#define NACT 448    // x(64) | read(128) | ctrl(256)
#define EPSF 1e-6f

// fp16 weight panel, CHUNK-TRANSPOSED layout (identical to prior rounds):
//   element(region, kc, col, e) at region_base + (kc*NCOLS + col)*8 + e
#define H_WA   0        // rz:    56 kc x 512 cols x 8
#define H_WNI  229376   // inn:   24 kc x 256 cols x 8
#define H_WNH  278528   // hn:    32 kc x 256 cols x 8
#define H_WH   344064   // heads: 32 kc x 512 cols x 8 (key|erase|add|beta|pad)
#define H_TOTAL 475136
#define B_BA   0        // [512] b_ih+b_hh (r,z)
#define B_BNI  512      // [256]
#define B_BNH  768      // [256]
#define B_BH   1024     // [512]
#define B_TOTAL 1536
#define WS_BYTES (H_TOTAL * 2 + B_TOTAL * 4)

typedef _Float16 h2 __attribute__((ext_vector_type(2)));
typedef _Float16 h8 __attribute__((ext_vector_type(8)));
union H8 { h8 v; h2 d[4]; };

__device__ __forceinline__ float sigf(float x) { return 1.0f / (1.0f + expf(-x)); }
__device__ __forceinline__ float softplusf(float x) {
    return (x > 15.0f) ? x : log1pf(expf(x));
}
__device__ __forceinline__ float fdot2(h2 a, h2 b, float c) {
#if __has_builtin(__builtin_amdgcn_fdot2)
    return __builtin_amdgcn_fdot2(a, b, c, false);
#else
    return fmaf((float)a[0], (float)b[0], fmaf((float)a[1], (float)b[1], c));
#endif
}

// lgkm-only barrier: orders LDS traffic without draining vmcnt (in-loop
// inter-thread communication is all via LDS; the compiler still inserts
// per-value vmcnt waits for each thread's own global loads).
// Verified correct in round 8 (passed, absmax identical to __syncthreads).
__device__ __forceinline__ void barL() {
    asm volatile("s_waitcnt lgkmcnt(0)\n\ts_barrier" ::: "memory");
}

__global__ __launch_bounds__(256) void prep_kernel(
    const float* __restrict__ Wih, const float* __restrict__ bih,
    const float* __restrict__ Whh, const float* __restrict__ bhh,
    const float* __restrict__ Wkey, const float* __restrict__ bkey,
    const float* __restrict__ Wbeta, const float* __restrict__ bbeta,
    const float* __restrict__ Wer, const float* __restrict__ ber,
    const float* __restrict__ Wadd, const float* __restrict__ badd,
    _Float16* __restrict__ wsH, float* __restrict__ wsB)
{
    int i = blockIdx.x * 256 + threadIdx.x;
    if (i < H_TOTAL) {
        float v;
        if (i < H_WNI) {                       // rz [kc][512][8]
            int ch = i >> 3, e = i & 7;
            int kc = ch >> 9, col = ch & 511;
            int k = kc * 8 + e;
            v = (k < 192) ? Wih[col * 192 + k] : Whh[col * 256 + (k - 192)];
        } else if (i < H_WNH) {                // inn [kc][256][8], k<192
            int i2 = i - H_WNI; int ch = i2 >> 3, e = i2 & 7;
            int kc = ch >> 8, col = ch & 255;
            v = Wih[(512 + col) * 192 + kc * 8 + e];
        } else if (i < H_WH) {                 // hn [kc][256][8], k<256
            int i2 = i - H_WNH; int ch = i2 >> 3, e = i2 & 7;
            int kc = ch >> 8, col = ch & 255;
            v = Whh[(512 + col) * 256 + kc * 8 + e];
        } else {                               // heads [kc][512][8], k<256
            int i2 = i - H_WH; int ch = i2 >> 3, e = i2 & 7;
            int kc = ch >> 9, col = ch & 511;
            int k = kc * 8 + e;
            if (col < 128)       v = Wkey[col * 256 + k];
            else if (col < 256)  v = Wer[(col - 128) * 256 + k];
            else if (col < 384)  v = Wadd[(col - 256) * 256 + k];
            else if (col == 384) v = Wbeta[k];
            else                 v = 0.0f;
        }
        wsH[i] = (_Float16)v;
    } else if (i < H_TOTAL + B_TOTAL) {
        int j = i - H_TOTAL;
        float v;
        if (j < 512)        v = bih[j] + bhh[j];
        else if (j < 768)   v = bih[512 + (j - 512)];
        else if (j < 1024)  v = bhh[512 + (j - 768)];
        else {
            int c = j - 1024;
            if (c < 128)       v = bkey[c];
            else if (c < 256)  v = ber[c - 128];
            else if (c < 384)  v = badd[c - 256];
            else if (c == 384) v = bbeta[0];
            else               v = 0.0f;
        }
        wsB[j] = v;
    }
}

// Verified memory module (used by slow path only).
__device__ __forceinline__ void memory_step(
    int u, bool wr, float (*M)[NWORD + 1],
    const float* keyv, const float* ev, const float* av,
    float* cosb, float* wb, float* part, float* readv, float* scal)
{
    if (u < 64) {                       // ||k||
        float s = keyv[u] * keyv[u] + keyv[u + 64] * keyv[u + 64];
        #pragma unroll
        for (int o = 32; o >= 1; o >>= 1) s += __shfl_xor(s, o);
        if (u == 0) scal[0] = 1.0f / (sqrtf(s) + EPSF);
    }
    __syncthreads();
    {                                      // cosine sim: 2 threads / row
        int rr = u >> 1, hh = u & 1;
        const float* Mr = &M[rr][hh * 64];
        const float4* kk4 = (const float4*)(keyv + hh * 64);
        float s2 = 0.f, sc = 0.f;
        #pragma unroll
        for (int p = 0; p < 16; ++p) {
            float4 k4 = kk4[p];
            float m0 = Mr[4 * p], m1 = Mr[4 * p + 1], m2 = Mr[4 * p + 2], m3 = Mr[4 * p + 3];
            s2 = fmaf(m0, m0, s2); sc = fmaf(m0, k4.x, sc);
            s2 = fmaf(m1, m1, s2); sc = fmaf(m1, k4.y, sc);
            s2 = fmaf(m2, m2, s2); sc = fmaf(m2, k4.z, sc);
            s2 = fmaf(m3, m3, s2); sc = fmaf(m3, k4.w, sc);
        }
        s2 += __shfl_xor(s2, 1);
        sc += __shfl_xor(sc, 1);
        if (hh == 0) cosb[rr] = sc * scal[0] / (sqrtf(s2) + EPSF);
    }
    __syncthreads();
    if (u < 64) {                       // softmax over 128 logits
        float beta = scal[1];
        float l0 = beta * cosb[u], l1 = beta * cosb[u + 64];
        float mx = fmaxf(l0, l1);
        #pragma unroll
        for (int o = 32; o >= 1; o >>= 1) mx = fmaxf(mx, __shfl_xor(mx, o));
        float e0 = expf(l0 - mx), e1 = expf(l1 - mx);
        float s = e0 + e1;
        #pragma unroll
        for (int o = 32; o >= 1; o >>= 1) s += __shfl_xor(s, o);
        float inv = 1.0f / s;
        wb[u] = e0 * inv;
        wb[u + 64] = e1 * inv;
    }
    __syncthreads();
    {   // FUSED read+update
        int j = u & 127, rh = u >> 7;
        float ej = ev[j], aj = av[j];
        const float4* wb4 = (const float4*)(wb + rh * 64);
        float p = 0.f;
        #pragma unroll
        for (int pq = 0; pq < 16; ++pq) {
            float4 w4 = wb4[pq];
            int r = rh * 64 + 4 * pq;
            float m0 = M[r][j], m1 = M[r + 1][j], m2 = M[r + 2][j], m3 = M[r + 3][j];
            p = fmaf(w4.x, m0, p);
            p = fmaf(w4.y, m1, p);
            p = fmaf(w4.z, m2, p);
            p = fmaf(w4.w, m3, p);
            if (wr) {
                M[r][j]     = fmaf(-w4.x, fmaf(ej, m0, -aj), m0);
                M[r + 1][j] = fmaf(-w4.y, fmaf(ej, m1, -aj), m1);
                M[r + 2][j] = fmaf(-w4.z, fmaf(ej, m2, -aj), m2);
                M[r + 3][j] = fmaf(-w4.w, fmaf(ej, m3, -aj), m3);
            }
        }
        part[rh * 128 + j] = p;
    }
    __syncthreads();
    if (wr && u < 128) readv[u] = part[u] + part[128 + u];
}

#define DOT_RZ(WSRC) do { H8 w_; w_.v = (WSRC); \
    a0 = fdot2(x0.d[0], w_.d[0], a0); c0 = fdot2(x0.d[1], w_.d[1], c0); \
    a0 = fdot2(x0.d[2], w_.d[2], a0); c0 = fdot2(x0.d[3], w_.d[3], c0); \
    a1 = fdot2(x1.d[0], w_.d[0], a1); c1 = fdot2(x1.d[1], w_.d[1], c1); \
    a1 = fdot2(x1.d[2], w_.d[2], a1); c1 = fdot2(x1.d[3], w_.d[3], c1); } while (0)

#define DOT_AUX(WSRC) do { H8 w_; w_.v = (WSRC); \
    e0 = fdot2(x0.d[0], w_.d[0], e0); f0 = fdot2(x0.d[1], w_.d[1], f0); \
    e0 = fdot2(x0.d[2], w_.d[2], e0); f0 = fdot2(x0.d[3], w_.d[3], f0); \
    e1 = fdot2(x1.d[0], w_.d[0], e1); f1 = fdot2(x1.d[1], w_.d[1], f1); \
    e1 = fdot2(x1.d[2], w_.d[2], e1); f1 = fdot2(x1.d[3], w_.d[3], f1); } while (0)

#define DOT_HD(WSRC) do { H8 w_; w_.v = (WSRC); \
    h0 = fdot2(x0.d[0], w_.d[0], h0); d0 = fdot2(x0.d[1], w_.d[1], d0); \
    h0 = fdot2(x0.d[2], w_.d[2], h0); d0 = fdot2(x0.d[3], w_.d[3], d0); \
    h1 = fdot2(x1.d[0], w_.d[0], h1); d1 = fdot2(x1.d[1], w_.d[1], d1); \
    h1 = fdot2(x1.d[2], w_.d[2], h1); d1 = fdot2(x1.d[3], w_.d[3], d1); } while (0)

#define LOADX(KC) H8 x0; x0.v = A0[KC]; H8 x1; x1.v = A1[KC]

// Round-2 structure EXACTLY (512 thr, 2 rows/block, long unroll-4 sweeps,
// 96-VGPR-class pressure) + three verified micro-levers from round 8:
//   (1) barL lgkm-only barriers (no per-barrier vmcnt drain),
//   (2) ||k||^2 folded into the heads phase (one less barrier + phase),
//   (3) x(t+1) prefetched into a register during the heads phase.
// NO sweep segmentation (round 8's regression: chopping the sweep into
// short segments broke the compiler's load streaming).
__global__ __launch_bounds__(512) void ntm_fast7(
    const float* __restrict__ data, const int* __restrict__ batch_sizes,
    const int* __restrict__ unsort, const float* __restrict__ M0,
    const _Float16* __restrict__ wsH, const float* __restrict__ wsB,
    float* __restrict__ out)
{
    __shared__ float M[2][NMEM][NWORD + 1];               // 132096 B
    __shared__ __align__(16) _Float16 actH[2][NACT];      // 1792 B
    __shared__ float ctrlB[2][NCTRL];
    __shared__ float gA[2][512];
    __shared__ float iA[2][NCTRL];
    __shared__ float hA[2][NCTRL];
    __shared__ __align__(16) float readv[2][NWORD], keyv[2][NWORD], ev[2][NWORD], av[2][NWORD];
    __shared__ __align__(16) float cosb[2][NMEM], wb[2][NMEM], part[2][2 * NWORD];
    __shared__ float kn2[2][2], betav[2];
    __shared__ int len_sh[2], gpos[2];

    const int t = threadIdx.x;
    const int q = t >> 8;          // row half (0/1)
    const int u = t & 255;         // local tid within half
    const int g = blockIdx.x;
    const int b = 2 * g + q;       // this half's packed row

    if (t < 2) {
        int bb = 2 * g + t;
        int L = 0;
        for (int s = 0; s < NT; ++s) L += (batch_sizes[s] > bb);
        len_sh[t] = L;
    }
    {   // inverse permutation: find out-position of each packed row
        int ug = unsort[t];                 // t in [0,512) == NB
        if (ug == 2 * g)     gpos[0] = t;
        if (ug == 2 * g + 1) gpos[1] = t;
    }
    for (int i = t; i < 2 * NMEM * NWORD; i += 512) {
        int ii = i & (NMEM * NWORD - 1);
        M[i >> 14][ii >> 7][ii & 127] = M0[ii];
    }
    ctrlB[q][u] = 0.0f;
    actH[q][192 + u] = (_Float16)0.0f;
    if (u < NWORD) readv[q][u] = 0.0f;
    __syncthreads();
    const int len0 = len_sh[0], len1 = len_sh[1];   // len0 >= len1 (packed order)

    const float bRZ  = wsB[B_BA + t];
    const float bAux = (t < 256) ? wsB[B_BNI + u] : wsB[B_BNH + u];
    const float bHD  = wsB[B_BH + t];

    const h8* __restrict__ pA  = (const h8*)(wsH + H_WA);
    const h8* __restrict__ pI  = (const h8*)(wsH + H_WNI);
    const h8* __restrict__ pH  = (const h8*)(wsH + H_WNH);
    const h8* __restrict__ pHD = (const h8*)(wsH + H_WH);
    const h8* A0 = (const h8*)actH[0];
    const h8* A1 = (const h8*)actH[1];

    float xf = 0.0f;
    if (u >= 128 && u < 192) xf = data[((long)0 * NB + b) * NDIN + (u - 128)];

    for (int ts = 0; ts < len0; ++ts) {
        const bool wr = (q == 0) | (ts < len1);
        // ---- stage activations as fp16 (state masters stay fp32)
        if (u < 128)      actH[q][64 + u] = (_Float16)readv[q][u];
        else if (u < 192) actH[q][u - 128] = (_Float16)xf;
        barL();

        // ---- fused sweep: rz col t (both rows) + aux col u  [round-2 loops]
        float a0 = bRZ, c0 = 0.f, a1 = bRZ, c1 = 0.f;
        float e0 = bAux, f0 = 0.f, e1 = bAux, f1 = 0.f;
        if (t < 256) {
            #pragma unroll 4
            for (int kc = 0; kc < 24; ++kc) {            // k in [0,192): rz + inn
                LOADX(kc);
                DOT_RZ(pA[kc * 512 + t]);
                DOT_AUX(pI[kc * 256 + u]);
            }
            #pragma unroll 4
            for (int kc = 24; kc < 56; ++kc) {           // k in [192,448): rz only
                LOADX(kc);
                DOT_RZ(pA[kc * 512 + t]);
            }
        } else {
            #pragma unroll 4
            for (int kc = 0; kc < 24; ++kc) {            // rz only
                LOADX(kc);
                DOT_RZ(pA[kc * 512 + t]);
            }
            #pragma unroll 4
            for (int kc = 24; kc < 56; ++kc) {           // rz + hn
                LOADX(kc);
                DOT_RZ(pA[kc * 512 + t]);
                DOT_AUX(pH[(kc - 24) * 256 + u]);
            }
        }
        gA[0][t] = a0 + c0;
        gA[1][t] = a1 + c1;
        if (t < 256) { iA[0][u] = e0 + f0; iA[1][u] = e1 + f1; }
        else         { hA[0][u] = e0 + f0; hA[1][u] = e1 + f1; }
        barL();

        {   // gate combine: thread (q,u) owns ctrl element u of row q
            float rg = sigf(gA[q][u]);
            float zg = sigf(gA[q][NCTRL + u]);
            float ng = tanhf(fmaf(rg, hA[q][u], iA[q][u]));
            float cold = ctrlB[q][u];
            float cnew = fmaf(zg, cold - ng, ng);
            if (wr) {
                ctrlB[q][u] = cnew;
                actH[q][192 + u] = (_Float16)cnew;
            }
        }
        barL();

        // ---- heads: col t for both rows + kn2 fold + x(ts+1) prefetch
        {
            float h0 = bHD, d0 = 0.f, h1 = bHD, d1 = 0.f;
            #pragma unroll 4
            for (int kc = 0; kc < 32; ++kc) {
                LOADX(24 + kc);
                DOT_HD(pHD[kc * 512 + t]);
            }
            h0 += d0; h1 += d1;
            if (t < 128) {
                float k0 = tanhf(h0), k1 = tanhf(h1);
                keyv[0][t] = k0; keyv[1][t] = k1;
                // fold ||k||^2: per-wave butterfly, 2 partials per row
                float s0 = k0 * k0, s1 = k1 * k1;
                #pragma unroll
                for (int o = 32; o >= 1; o >>= 1) {
                    s0 += __shfl_xor(s0, o);
                    s1 += __shfl_xor(s1, o);
                }
                if ((t & 63) == 0) { kn2[0][t >> 6] = s0; kn2[1][t >> 6] = s1; }
            }
            else if (t < 256)  { ev[0][t - 128] = sigf(h0); ev[1][t - 128] = sigf(h1); }
            else if (t < 384)  { av[0][t - 256] = h0;       av[1][t - 256] = h1; }
            else if (t == 384) { betav[0] = softplusf(h0);  betav[1] = softplusf(h1); }
            // prefetch next x; lands during the memory phases below
            int tn = (ts + 1 < NT) ? (ts + 1) : (NT - 1);
            if (u >= 128 && u < 192) xf = data[((long)tn * NB + b) * NDIN + (u - 128)];
        }
        barL();

        // ---- cosine sim (2 threads / mem-row); uses kn2 (no ||k|| phase)
        {
            float invk = 1.0f / (sqrtf(kn2[q][0] + kn2[q][1]) + EPSF);
            int rr = u >> 1, hh = u & 1;
            const float* Mr = &M[q][rr][hh * 64];
            const float4* kk4 = (const float4*)(&keyv[q][hh * 64]);
            float s2 = 0.f, sc = 0.f;
            #pragma unroll
            for (int p = 0; p < 16; ++p) {
                float4 k4 = kk4[p];
                float m0 = Mr[4 * p], m1 = Mr[4 * p + 1], m2 = Mr[4 * p + 2], m3 = Mr[4 * p + 3];
                s2 = fmaf(m0, m0, s2); sc = fmaf(m0, k4.x, sc);
                s2 = fmaf(m1, m1, s2); sc = fmaf(m1, k4.y, sc);
                s2 = fmaf(m2, m2, s2); sc = fmaf(m2, k4.z, sc);
                s2 = fmaf(m3, m3, s2); sc = fmaf(m3, k4.w, sc);
            }
            s2 += __shfl_xor(s2, 1);
            sc += __shfl_xor(sc, 1);
            if (hh == 0) cosb[q][rr] = sc * invk / (sqrtf(s2) + EPSF);
        }
        barL();

        // ---- softmax over 128 logits (64 threads per half)
        if (u < 64) {
            float beta = betav[q];
            float l0 = beta * cosb[q][u], l1 = beta * cosb[q][u + 64];
            float mx = fmaxf(l0, l1);
            #pragma unroll
            for (int o = 32; o >= 1; o >>= 1) mx = fmaxf(mx, __shfl_xor(mx, o));
            float se0 = expf(l0 - mx), se1 = expf(l1 - mx);
            float s = se0 + se1;
            #pragma unroll
            for (int o = 32; o >= 1; o >>= 1) s += __shfl_xor(s, o);
            float inv = 1.0f / s;
            wb[q][u] = se0 * inv;
            wb[q][u + 64] = se1 * inv;
        }
        barL();

        // ---- FUSED read+update
        {
            int j = u & 127, rh = u >> 7;
            float ej = ev[q][j], aj = av[q][j];
            const float4* wb4 = (const float4*)(&wb[q][rh * 64]);
            float p = 0.f;
            #pragma unroll
            for (int pq = 0; pq < 16; ++pq) {
                float4 w4 = wb4[pq];
                int r = rh * 64 + 4 * pq;
                float m0 = M[q][r][j], m1 = M[q][r + 1][j], m2 = M[q][r + 2][j], m3 = M[q][r + 3][j];
                p = fmaf(w4.x, m0, p);
                p = fmaf(w4.y, m1, p);
                p = fmaf(w4.z, m2, p);
                p = fmaf(w4.w, m3, p);
                if (wr) {
                    M[q][r][j]     = fmaf(-w4.x, fmaf(ej, m0, -aj), m0);
                    M[q][r + 1][j] = fmaf(-w4.y, fmaf(ej, m1, -aj), m1);
                    M[q][r + 2][j] = fmaf(-w4.z, fmaf(ej, m2, -aj), m2);
                    M[q][r + 3][j] = fmaf(-w4.w, fmaf(ej, m3, -aj), m3);
                }
            }
            part[q][rh * 128 + j] = p;
        }
        barL();
        if (wr && u < 128) readv[q][u] = part[q][u] + part[q][128 + u];
        // readv[u] produced and consumed by thread u -> no barrier here
    }

    out[gpos[q] * NCTRL + u] = ctrlB[q][u];
    if (u < NWORD) out[NB * NCTRL + gpos[q] * NWORD + u] = readv[q][u];
}

// FALLBACK (ws too small): verified slow path.
__global__ __launch_bounds__(256) void ntm_slow(
    const float* __restrict__ data, const int* __restrict__ batch_sizes,
    const int* __restrict__ unsort,
    const float* __restrict__ Wih, const float* __restrict__ bih,
    const float* __restrict__ Whh, const float* __restrict__ bhh,
    const float* __restrict__ Wkey, const float* __restrict__ bkey,
    const float* __restrict__ Wbeta, const float* __restrict__ bbeta,
    const float* __restrict__ Wer, const float* __restrict__ ber,
    const float* __restrict__ Wadd, const float* __restrict__ badd,
    const float* __restrict__ M0, float* __restrict__ out)
{
    __shared__ float M[NMEM][NWORD + 1];
    __shared__ float act[NACT];
    __shared__ float ctrlB[NCTRL];
    __shared__ float gpre[512], ginn[256], ghn[256], hpre[448];
    __shared__ __align__(16) float readv[NWORD], keyv[NWORD], ev[NWORD], av[NWORD];
    __shared__ __align__(16) float cosb[NMEM], wb[NMEM], part[2 * NWORD], scal[2];
    __shared__ int len_sh;

    const int tid = threadIdx.x;
    const int g = blockIdx.x;
    const int b = unsort[g];

    if (tid == 0) {
        int L = 0;
        for (int t = 0; t < NT; ++t) L += (batch_sizes[t] > b);
        len_sh = L;
    }
    for (int i = tid; i < NMEM * NWORD; i += 256)
        M[i >> 7][i & 127] = M0[i];
    ctrlB[tid] = 0.0f;
    if (tid < NWORD) readv[tid] = 0.0f;
    __syncthreads();
    const int len = len_sh;
    const int wave = tid >> 6, lane = tid & 63;

    for (int t = 0; t < len; ++t) {
        if (tid < 64)  act[tid] = data[((long)t * NB + b) * NDIN + tid];
        if (tid < 128) act[64 + tid] = readv[tid];
        act[192 + tid] = ctrlB[tid];
        __syncthreads();

        for (int j = wave; j < 512; j += 4) {
            float p = 0.f;
            for (int k = lane; k < 192; k += 64) p = fmaf(act[k], Wih[j * 192 + k], p);
            for (int k = lane; k < 256; k += 64) p = fmaf(act[192 + k], Whh[j * 256 + k], p);
            #pragma unroll
            for (int o = 32; o >= 1; o >>= 1) p += __shfl_xor(p, o);
            if (lane == 0) gpre[j] = p;
        }
        for (int j = wave; j < 256; j += 4) {
            float pi = 0.f, ph = 0.f;
            for (int k = lane; k < 192; k += 64) pi = fmaf(act[k], Wih[(512 + j) * 192 + k], pi);
            for (int k = lane; k < 256; k += 64) ph = fmaf(act[192 + k], Whh[(512 + j) * 256 + k], ph);
            #pragma unroll
            for (int o = 32; o >= 1; o >>= 1) { pi += __shfl_xor(pi, o); ph += __shfl_xor(ph, o); }
            if (lane == 0) { ginn[j] = pi; ghn[j] = ph; }
        }
        __syncthreads();
        {
            float r = sigf(gpre[tid] + bih[tid] + bhh[tid]);
            float z = sigf(gpre[256 + tid] + bih[256 + tid] + bhh[256 + tid]);
            float inn = ginn[tid] + bih[512 + tid];
            float hn  = ghn[tid] + bhh[512 + tid];
            float n = tanhf(fmaf(r, hn, inn));
            float cold = act[192 + tid];
            ctrlB[tid] = fmaf(z, cold - n, n);
        }
        __syncthreads();
        for (int j = wave; j < 385; j += 4) {
            const float* Wp; long base;
            if (j < 128)      { Wp = Wkey;  base = (long)j * 256; }
            else if (j < 256) { Wp = Wer;   base = (long)(j - 128) * 256; }
            else if (j < 384) { Wp = Wadd;  base = (long)(j - 256) * 256; }
            else              { Wp = Wbeta; base = 0; }
            float p = 0.f;
            for (int k = lane; k < 256; k += 64) p = fmaf(ctrlB[k], Wp[base + k], p);
            #pragma unroll
            for (int o = 32; o >= 1; o >>= 1) p += __shfl_xor(p, o);
            if (lane == 0) hpre[j] = p;
        }
        __syncthreads();
        if (tid < 128) {
            keyv[tid] = tanhf(hpre[tid] + bkey[tid]);
            ev[tid]   = sigf(hpre[128 + tid] + ber[tid]);
            av[tid]   = hpre[256 + tid] + badd[tid];
        }
        if (tid == 0) scal[1] = softplusf(hpre[384] + bbeta[0]);
        __syncthreads();

        memory_step(tid, true, M, keyv, ev, av, cosb, wb, part, readv, scal);
        __syncthreads();
    }

    out[g * NCTRL + tid] = ctrlB[tid];
    if (tid < NWORD) out[NB * NCTRL + g * NWORD + tid] = readv[tid];
}

extern "C" void kernel_launch(void* const* d_in, const int* in_sizes, int n_in,
                              void* d_out, int out_size, void* d_ws, size_t ws_size,
                              hipStream_t stream)
{
    const float* data       = (const float*)d_in[0];
    const int*  batch_sizes = (const int*)d_in[1];
    const int*  unsort      = (const int*)d_in[2];
    float* out = (float*)d_out;

    if (ws_size >= (size_t)WS_BYTES) {
        _Float16* wsH = (_Float16*)d_ws;
        float* wsB = (float*)((char*)d_ws + (size_t)H_TOTAL * 2);
        prep_kernel<<<(H_TOTAL + B_TOTAL + 255) / 256, 256, 0, stream>>>(
            (const float*)d_in[3], (const float*)d_in[4], (const float*)d_in[5],
            (const float*)d_in[6], (const float*)d_in[7], (const float*)d_in[8],
            (const float*)d_in[9], (const float*)d_in[10], (const float*)d_in[11],
            (const float*)d_in[12], (const float*)d_in[13], (const float*)d_in[14],
            wsH, wsB);
        ntm_fast7<<<NB / 2, 512, 0, stream>>>(data, batch_sizes, unsort,
                                              (const float*)d_in[15], wsH, wsB, out);
    } else {
        ntm_slow<<<NB, 256, 0, stream>>>(
            data, batch_sizes, unsort,
            (const float*)d_in[3], (const float*)d_in[4], (const float*)d_in[5],
            (const float*)d_in[6], (const float*)d_in[7], (const float*)d_in[8],
            (const float*)d_in[9], (const float*)d_in[10], (const float*)d_in[11],
            (const float*)d_in[12], (const float*)d_in[13], (const float*)d_in[14],
            (const float*)d_in[15], out);
    }
}